// Round 2
// baseline (299.944 us; speedup 1.0000x reference)
//
#include <hip/hip_runtime.h>
#include <hip/hip_bf16.h>

// SASA local self-attention, fused single kernel, online-softmax (no lg[49] spills).
// B=4, CIN=COUT=256, H=W=64, G=8, CG=32, K=7, PAD=3.
#define TS   16          // spatial tile (16x16 outputs per block)
#define HS   22          // halo tile side = TS + K-1
#define HP   484         // HS*HS
#define KSTR 36          // LDS row stride in bf16 elems (72B: 8B-aligned, 2-way max on b64)
#define CG   32
#define CIG  32
#define KK   7
#define K2   49

__device__ __forceinline__ float bflo(unsigned u){ return __uint_as_float(u << 16); }
__device__ __forceinline__ float bfhi(unsigned u){ return __uint_as_float(u & 0xffff0000u); }
__device__ __forceinline__ unsigned bfpack(float a, float b){
    // pack two fp32 -> two bf16 (RNE) in one u32
    __hip_bfloat162 h2 = __float22bfloat162_rn(make_float2(a, b));
    union { __hip_bfloat162 h; unsigned u; } c; c.h = h2; return c.u;
}

__global__ __launch_bounds__(256, 2)
void sasa_fused_kernel(const float* __restrict__ x,
                       const float* __restrict__ wq,
                       const float* __restrict__ wk,
                       const float* __restrict__ wv,
                       const float* __restrict__ row_emb,
                       const float* __restrict__ col_emb,
                       float* __restrict__ out)
{
    __shared__ float s_w[2048];                 // [0:1024)=w_k then w_q then qe[256][7]; [1024:2048)=w_v
    __shared__ float s_emb[CG * KK];            // E[c][t] for this group
    __shared__ __hip_bfloat16 s_k[HP * KSTR];
    __shared__ __hip_bfloat16 s_v[HP * KSTR];

    const int tid = threadIdx.x;
    const int bz  = blockIdx.z;
    const int b   = bz >> 3;
    const int g   = bz & 7;
    const int y0  = blockIdx.y * TS;
    const int x0  = blockIdx.x * TS;

    // ---- stage w_k, w_v (fp32) + emb slice ----
    #pragma unroll
    for (int i = 0; i < 4; ++i) {
        s_w[tid + i * 256]        = wk[g * 1024 + tid + i * 256];
        s_w[1024 + tid + i * 256] = wv[g * 1024 + tid + i * 256];
    }
    if (tid < CG * KK) {
        int c = tid / KK, t = tid - c * KK;
        s_emb[tid] = (g < 4) ? row_emb[(g * CG + c) * KK + t]
                             : col_emb[((g - 4) * CG + c) * KK + t];
    }
    __syncthreads();

    const float* xg = x + (size_t)(b * 256 + g * CG) * 4096;

    // ---- halo K/V projection -> LDS (bf16, packed b32 stores) ----
    for (int hp = tid; hp < HP; hp += 256) {
        int hy = hp / HS, hx = hp - hy * HS;
        int gy = y0 + hy - 3, gx = x0 + hx - 3;
        float kacc[CG], vacc[CG];
        #pragma unroll
        for (int c = 0; c < CG; ++c) { kacc[c] = 0.f; vacc[c] = 0.f; }
        if ((unsigned)gy < 64u && (unsigned)gx < 64u) {
            const float* xp = xg + gy * 64 + gx;
            #pragma unroll 4
            for (int ci = 0; ci < CIG; ++ci) {
                float xv = xp[ci * 4096];
                #pragma unroll
                for (int co = 0; co < CG; ++co) {
                    kacc[co] = fmaf(s_w[co * CIG + ci],        xv, kacc[co]);
                    vacc[co] = fmaf(s_w[1024 + co * CIG + ci], xv, vacc[co]);
                }
            }
        }
        unsigned* kd = (unsigned*)(s_k + hp * KSTR);
        unsigned* vd = (unsigned*)(s_v + hp * KSTR);
        #pragma unroll
        for (int c = 0; c < CG; c += 2) {
            kd[c >> 1] = bfpack(kacc[c], kacc[c + 1]);
            vd[c >> 1] = bfpack(vacc[c], vacc[c + 1]);
        }
    }
    __syncthreads();

    // ---- reuse w_k slot for w_q ----
    #pragma unroll
    for (int i = 0; i < 4; ++i)
        s_w[tid + i * 256] = wq[g * 1024 + tid + i * 256];
    __syncthreads();

    // ---- q projection (registers) ----
    const int tx = tid & 15, ty = tid >> 4;
    const int yy = y0 + ty, xx = x0 + tx;
    float q[CG];
    #pragma unroll
    for (int c = 0; c < CG; ++c) q[c] = 0.f;
    {
        const float* xp = xg + yy * 64 + xx;
        #pragma unroll 4
        for (int ci = 0; ci < CIG; ++ci) {
            float xv = xp[ci * 4096];
            #pragma unroll
            for (int co = 0; co < CG; ++co)
                q[co] = fmaf(s_w[co * CIG + ci], xv, q[co]);
        }
    }

    // ---- q . emb -> qe[7]; park in LDS (aliasing dead w_q slot) so the
    //      attention loop can index it at runtime without scratch ----
    float qe[KK];
    #pragma unroll
    for (int t = 0; t < KK; ++t) {
        float a = 0.f;
        #pragma unroll
        for (int c = 0; c < CG; ++c) a = fmaf(q[c], s_emb[c * KK + t], a);
        qe[t] = a;
    }
    __syncthreads();                       // all q-proj reads of w_q done
    float* s_qe = s_w + tid * KK;          // private 7-float slot per thread
    #pragma unroll
    for (int t = 0; t < KK; ++t) s_qe[t] = qe[t];
    // own-thread readback: no barrier needed

    // ---- online-softmax attention (no logit array) ----
    const int rowsel = (g < 4) ? 1 : 0;
    float m = -3.0e38f, d = 0.f;
    float o[CG];
    #pragma unroll
    for (int c = 0; c < CG; ++c) o[c] = 0.f;

    #pragma unroll 1
    for (int ki = 0; ki < KK; ++ki) {
        const int hprow = (ty + ki) * HS + tx;
        #pragma unroll
        for (int kj = 0; kj < KK; ++kj) {
            const int hp = hprow + kj;
            float add = s_qe[rowsel ? ki : kj];
            const uint2* kp = (const uint2*)(s_k + hp * KSTR);
            const uint2* vp = (const uint2*)(s_v + hp * KSTR);
            float acc = add;
            #pragma unroll
            for (int j = 0; j < 8; ++j) {
                uint2 w = kp[j];
                acc = fmaf(bflo(w.x), q[4 * j + 0], acc);
                acc = fmaf(bfhi(w.x), q[4 * j + 1], acc);
                acc = fmaf(bflo(w.y), q[4 * j + 2], acc);
                acc = fmaf(bfhi(w.y), q[4 * j + 3], acc);
            }
            float pm   = fmaxf(m, acc);
            float corr = __expf(m - pm);       // first iter: exp(-huge) = 0
            float p    = __expf(acc - pm);
            d = fmaf(d, corr, p);
            m = pm;
            #pragma unroll
            for (int j = 0; j < 8; ++j) {
                uint2 w = vp[j];
                o[4 * j + 0] = fmaf(bflo(w.x), p, o[4 * j + 0] * corr);
                o[4 * j + 1] = fmaf(bfhi(w.x), p, o[4 * j + 1] * corr);
                o[4 * j + 2] = fmaf(bflo(w.y), p, o[4 * j + 2] * corr);
                o[4 * j + 3] = fmaf(bfhi(w.y), p, o[4 * j + 3] * corr);
            }
        }
    }

    // ---- write ----
    float inv = 1.0f / d;
    float* op = out + (size_t)(b * 256 + g * CG) * 4096 + yy * 64 + xx;
    #pragma unroll
    for (int c = 0; c < CG; ++c)
        op[c * 4096] = o[c] * inv;
}

extern "C" void kernel_launch(void* const* d_in, const int* in_sizes, int n_in,
                              void* d_out, int out_size, void* d_ws, size_t ws_size,
                              hipStream_t stream) {
    const float* x       = (const float*)d_in[0];
    const float* wq      = (const float*)d_in[1];
    const float* wk      = (const float*)d_in[2];
    const float* wv      = (const float*)d_in[3];
    const float* row_emb = (const float*)d_in[4];
    const float* col_emb = (const float*)d_in[5];
    float* out = (float*)d_out;

    dim3 grid(4, 4, 32);   // (W/16, H/16, B*G)
    dim3 block(256);
    sasa_fused_kernel<<<grid, block, 0, stream>>>(x, wq, wk, wv, row_emb, col_emb, out);
}

// Round 3
// 299.161 us; speedup vs baseline: 1.0026x; 1.0026x over previous
//
#include <hip/hip_runtime.h>
#include <hip/hip_bf16.h>

// SASA local self-attention, fused single kernel, online-softmax.
// Round 3: pin waves/EU to 2 so the allocator can use 256 VGPRs (kill scratch spills).
// B=4, CIN=COUT=256, H=W=64, G=8, CG=32, K=7, PAD=3.
#define TS   16          // spatial tile (16x16 outputs per block)
#define HS   22          // halo tile side = TS + K-1
#define HP   484         // HS*HS
#define KSTR 36          // LDS row stride in bf16 elems (72B: 8B-aligned, 2-way max on b64)
#define CG   32
#define CIG  32
#define KK   7
#define K2   49

__device__ __forceinline__ float bflo(unsigned u){ return __uint_as_float(u << 16); }
__device__ __forceinline__ float bfhi(unsigned u){ return __uint_as_float(u & 0xffff0000u); }
__device__ __forceinline__ unsigned bfpack(float a, float b){
    __hip_bfloat162 h2 = __float22bfloat162_rn(make_float2(a, b));
    union { __hip_bfloat162 h; unsigned u; } c; c.h = h2; return c.u;
}

__global__ __attribute__((amdgpu_flat_work_group_size(256, 256), amdgpu_waves_per_eu(2, 2)))
void sasa_fused_kernel(const float* __restrict__ x,
                       const float* __restrict__ wq,
                       const float* __restrict__ wk,
                       const float* __restrict__ wv,
                       const float* __restrict__ row_emb,
                       const float* __restrict__ col_emb,
                       float* __restrict__ out)
{
    __shared__ float s_w[2048];                 // [0:1024)=w_k then w_q then qe[256][7]; [1024:2048)=w_v
    __shared__ float s_emb[CG * KK];            // E[c][t] for this group
    __shared__ __hip_bfloat16 s_k[HP * KSTR];
    __shared__ __hip_bfloat16 s_v[HP * KSTR];

    const int tid = threadIdx.x;
    const int bz  = blockIdx.z;
    const int b   = bz >> 3;
    const int g   = bz & 7;
    const int y0  = blockIdx.y * TS;
    const int x0  = blockIdx.x * TS;

    // ---- stage w_k, w_v (fp32) + emb slice ----
    #pragma unroll
    for (int i = 0; i < 4; ++i) {
        s_w[tid + i * 256]        = wk[g * 1024 + tid + i * 256];
        s_w[1024 + tid + i * 256] = wv[g * 1024 + tid + i * 256];
    }
    if (tid < CG * KK) {
        int c = tid / KK, t = tid - c * KK;
        s_emb[tid] = (g < 4) ? row_emb[(g * CG + c) * KK + t]
                             : col_emb[((g - 4) * CG + c) * KK + t];
    }
    __syncthreads();

    const float* xg = x + (size_t)(b * 256 + g * CG) * 4096;

    // ---- halo K/V projection -> LDS (bf16, packed b32 stores) ----
    for (int hp = tid; hp < HP; hp += 256) {
        int hy = hp / HS, hx = hp - hy * HS;
        int gy = y0 + hy - 3, gx = x0 + hx - 3;
        float kacc[CG], vacc[CG];
        #pragma unroll
        for (int c = 0; c < CG; ++c) { kacc[c] = 0.f; vacc[c] = 0.f; }
        if ((unsigned)gy < 64u && (unsigned)gx < 64u) {
            const float* xp = xg + gy * 64 + gx;
            #pragma unroll 4
            for (int ci = 0; ci < CIG; ++ci) {
                float xv = xp[ci * 4096];
                #pragma unroll
                for (int co = 0; co < CG; ++co) {
                    kacc[co] = fmaf(s_w[co * CIG + ci],        xv, kacc[co]);
                    vacc[co] = fmaf(s_w[1024 + co * CIG + ci], xv, vacc[co]);
                }
            }
        }
        unsigned* kd = (unsigned*)(s_k + hp * KSTR);
        unsigned* vd = (unsigned*)(s_v + hp * KSTR);
        #pragma unroll
        for (int c = 0; c < CG; c += 2) {
            kd[c >> 1] = bfpack(kacc[c], kacc[c + 1]);
            vd[c >> 1] = bfpack(vacc[c], vacc[c + 1]);
        }
    }
    __syncthreads();

    // ---- reuse w_k slot for w_q ----
    #pragma unroll
    for (int i = 0; i < 4; ++i)
        s_w[tid + i * 256] = wq[g * 1024 + tid + i * 256];
    __syncthreads();

    // ---- q projection (registers) ----
    const int tx = tid & 15, ty = tid >> 4;
    const int yy = y0 + ty, xx = x0 + tx;
    float q[CG];
    #pragma unroll
    for (int c = 0; c < CG; ++c) q[c] = 0.f;
    {
        const float* xp = xg + yy * 64 + xx;
        #pragma unroll 4
        for (int ci = 0; ci < CIG; ++ci) {
            float xv = xp[ci * 4096];
            #pragma unroll
            for (int co = 0; co < CG; ++co)
                q[co] = fmaf(s_w[co * CIG + ci], xv, q[co]);
        }
    }

    // ---- q . emb -> qe[7]; park in LDS (aliasing dead w_q slot) so the
    //      attention loop can index it at runtime without scratch ----
    float qe[KK];
    #pragma unroll
    for (int t = 0; t < KK; ++t) {
        float a = 0.f;
        #pragma unroll
        for (int c = 0; c < CG; ++c) a = fmaf(q[c], s_emb[c * KK + t], a);
        qe[t] = a;
    }
    __syncthreads();                       // all q-proj reads of w_q done
    float* s_qe = s_w + tid * KK;          // private 7-float slot per thread
    #pragma unroll
    for (int t = 0; t < KK; ++t) s_qe[t] = qe[t];
    // own-thread readback: no barrier needed

    // ---- online-softmax attention (no logit array) ----
    const int rowsel = (g < 4) ? 1 : 0;
    float m = -3.0e38f, d = 0.f;
    float o[CG];
    #pragma unroll
    for (int c = 0; c < CG; ++c) o[c] = 0.f;

    #pragma unroll 1
    for (int ki = 0; ki < KK; ++ki) {
        const int hprow = (ty + ki) * HS + tx;
        #pragma unroll
        for (int kj = 0; kj < KK; ++kj) {
            const int hp = hprow + kj;
            float add = s_qe[rowsel ? ki : kj];
            const uint2* kp = (const uint2*)(s_k + hp * KSTR);
            const uint2* vp = (const uint2*)(s_v + hp * KSTR);
            float acc = add;
            #pragma unroll
            for (int j = 0; j < 8; ++j) {
                uint2 w = kp[j];
                acc = fmaf(bflo(w.x), q[4 * j + 0], acc);
                acc = fmaf(bfhi(w.x), q[4 * j + 1], acc);
                acc = fmaf(bflo(w.y), q[4 * j + 2], acc);
                acc = fmaf(bfhi(w.y), q[4 * j + 3], acc);
            }
            float pm   = fmaxf(m, acc);
            float corr = __expf(m - pm);       // first iter: exp(-huge) = 0
            float p    = __expf(acc - pm);
            d = fmaf(d, corr, p);
            m = pm;
            #pragma unroll
            for (int j = 0; j < 8; ++j) {
                uint2 w = vp[j];
                o[4 * j + 0] = fmaf(bflo(w.x), p, o[4 * j + 0] * corr);
                o[4 * j + 1] = fmaf(bfhi(w.x), p, o[4 * j + 1] * corr);
                o[4 * j + 2] = fmaf(bflo(w.y), p, o[4 * j + 2] * corr);
                o[4 * j + 3] = fmaf(bfhi(w.y), p, o[4 * j + 3] * corr);
            }
        }
    }

    // ---- write ----
    float inv = 1.0f / d;
    float* op = out + (size_t)(b * 256 + g * CG) * 4096 + yy * 64 + xx;
    #pragma unroll
    for (int c = 0; c < CG; ++c)
        op[c * 4096] = o[c] * inv;
}

extern "C" void kernel_launch(void* const* d_in, const int* in_sizes, int n_in,
                              void* d_out, int out_size, void* d_ws, size_t ws_size,
                              hipStream_t stream) {
    const float* x       = (const float*)d_in[0];
    const float* wq      = (const float*)d_in[1];
    const float* wk      = (const float*)d_in[2];
    const float* wv      = (const float*)d_in[3];
    const float* row_emb = (const float*)d_in[4];
    const float* col_emb = (const float*)d_in[5];
    float* out = (float*)d_out;

    dim3 grid(4, 4, 32);   // (W/16, H/16, B*G)
    dim3 block(256);
    sasa_fused_kernel<<<grid, block, 0, stream>>>(x, wq, wk, wv, row_emb, col_emb, out);
}

// Round 8
// 107.577 us; speedup vs baseline: 2.7882x; 2.7809x over previous
//
#include <hip/hip_runtime.h>
#include <hip/hip_bf16.h>

// SASA local self-attention, fused, lane-paired channel-split (max ~16 accs/thread).
// B=4, CIN=COUT=256, H=W=64, G=8, CG=32, K=7, PAD=3.
// (4th resubmission of round-4 kernel — container unresponsive four times.)
#define TS   16          // spatial tile (16x16 outputs per block)
#define HS   22          // halo tile side = TS + K-1
#define HP   484         // HS*HS
#define KSTR 36          // LDS row stride in bf16 elems (72B: 8B-aligned, 2-way max on b64)
#define KK   7

__device__ __forceinline__ float bflo(unsigned u){ return __uint_as_float(u << 16); }
__device__ __forceinline__ float bfhi(unsigned u){ return __uint_as_float(u & 0xffff0000u); }
__device__ __forceinline__ unsigned bfpack(float a, float b){
    __hip_bfloat162 h2 = __float22bfloat162_rn(make_float2(a, b));
    union { __hip_bfloat162 h; unsigned u; } c; c.h = h2; return c.u;
}

__global__ __launch_bounds__(512, 4)
void sasa_fused_kernel(const float* __restrict__ x,
                       const float* __restrict__ wq,
                       const float* __restrict__ wk,
                       const float* __restrict__ wv,
                       const float* __restrict__ row_emb,
                       const float* __restrict__ col_emb,
                       float* __restrict__ out)
{
    __shared__ float s_w[2048];            // [0:1024)=w_k, later w_q, later qe[256][7]; [1024:2048)=w_v
    __shared__ float s_emb[224];           // E[c][t] for this group (32 x 7)
    __shared__ __hip_bfloat16 s_k[HP * KSTR];
    __shared__ __hip_bfloat16 s_v[HP * KSTR];

    const int tid = threadIdx.x;
    const int bz  = blockIdx.z;
    const int b   = bz >> 3;
    const int g   = bz & 7;
    const int y0  = blockIdx.y * TS;
    const int x0  = blockIdx.x * TS;

    // ---- stage w_k, w_v (fp32) + emb slice ----
    #pragma unroll
    for (int i = 0; i < 2; ++i) {
        s_w[tid + i * 512]        = wk[g * 1024 + tid + i * 512];
        s_w[1024 + tid + i * 512] = wv[g * 1024 + tid + i * 512];
    }
    if (tid < 224) {
        int c = tid / KK, t = tid - c * KK;
        s_emb[tid] = (g < 4) ? row_emb[(g * 32 + c) * KK + t]
                             : col_emb[((g - 4) * 32 + c) * KK + t];
    }
    __syncthreads();

    const float* xg = x + (size_t)(b * 256 + g * 32) * 4096;

    // ---- halo K/V projection -> LDS (bf16). Work item = (hp, kv, half): 16 accs. ----
    for (int it = tid; it < HP * 4; it += 512) {
        const int hp = it >> 2;
        const int kv = (it >> 1) & 1;
        const int hh = it & 1;
        const int hy = hp / HS, hx = hp - hy * HS;
        const int gy = y0 + hy - 3, gx = x0 + hx - 3;
        float acc[16];
        #pragma unroll
        for (int c = 0; c < 16; ++c) acc[c] = 0.f;
        if ((unsigned)gy < 64u && (unsigned)gx < 64u) {
            const float* xp = xg + gy * 64 + gx;
            const float* wb = s_w + kv * 1024 + hh * 512;   // w[co_local][ci], co base hh*16
            #pragma unroll 4
            for (int ci = 0; ci < 32; ++ci) {
                float xv = xp[ci * 4096];
                #pragma unroll
                for (int co = 0; co < 16; ++co)
                    acc[co] = fmaf(wb[co * 32 + ci], xv, acc[co]);
            }
        }
        __hip_bfloat16* dstb = (kv ? s_v : s_k) + hp * KSTR + hh * 16;
        unsigned* d32 = (unsigned*)dstb;                    // 4B-aligned (72*hp + 32*hh)
        #pragma unroll
        for (int j = 0; j < 8; ++j)
            d32[j] = bfpack(acc[2 * j], acc[2 * j + 1]);
    }
    __syncthreads();

    // ---- reuse w_k slot for w_q ----
    #pragma unroll
    for (int i = 0; i < 2; ++i)
        s_w[tid + i * 512] = wq[g * 1024 + tid + i * 512];
    __syncthreads();

    // ---- q projection: thread (p, h) owns 16 q channels ----
    const int p  = tid >> 1;
    const int h  = tid & 1;
    const int tx = p & 15, ty = p >> 4;
    const int yy = y0 + ty, xx = x0 + tx;
    float q[16];
    #pragma unroll
    for (int c = 0; c < 16; ++c) q[c] = 0.f;
    {
        const float* xp = xg + yy * 64 + xx;
        const float* wb = s_w + h * 512;
        #pragma unroll 4
        for (int ci = 0; ci < 32; ++ci) {
            float xv = xp[ci * 4096];
            #pragma unroll
            for (int co = 0; co < 16; ++co)
                q[co] = fmaf(wb[co * 32 + ci], xv, q[co]);
        }
    }

    // ---- qe[7] = q . emb (pair-combined); park per-pixel in LDS over dead w_q ----
    float qe[KK];
    #pragma unroll
    for (int t = 0; t < KK; ++t) {
        float a = 0.f;
        #pragma unroll
        for (int c = 0; c < 16; ++c)
            a = fmaf(q[c], s_emb[(h * 16 + c) * KK + t], a);
        qe[t] = a;
    }
    #pragma unroll
    for (int t = 0; t < KK; ++t)
        qe[t] += __shfl_xor(qe[t], 1, 64);
    __syncthreads();                       // all w_q reads complete before overwrite
    float* s_qe = s_w + p * KK;            // per-pixel 7-float slot (1792 floats < 2048)
    if (h == 0) {
        #pragma unroll
        for (int t = 0; t < KK; ++t) s_qe[t] = qe[t];
    }
    // pair lanes are in the same wave: no barrier needed for readback

    // ---- online-softmax attention; o[16] per thread ----
    const int rowsel = (g < 4) ? 1 : 0;
    float m = -3.0e38f, d = 0.f;
    float o[16];
    #pragma unroll
    for (int c = 0; c < 16; ++c) o[c] = 0.f;

    #pragma unroll 1
    for (int ki = 0; ki < KK; ++ki) {
        const int hprow = (ty + ki) * HS + tx;
        #pragma unroll
        for (int kj = 0; kj < KK; ++kj) {
            const int hp = hprow + kj;
            const uint2* kp = (const uint2*)(s_k + hp * KSTR + h * 16);
            const uint2* vp = (const uint2*)(s_v + hp * KSTR + h * 16);
            float part = 0.f;
            #pragma unroll
            for (int j = 0; j < 4; ++j) {
                uint2 w = kp[j];
                part = fmaf(bflo(w.x), q[4 * j + 0], part);
                part = fmaf(bfhi(w.x), q[4 * j + 1], part);
                part = fmaf(bflo(w.y), q[4 * j + 2], part);
                part = fmaf(bfhi(w.y), q[4 * j + 3], part);
            }
            float lg = part + __shfl_xor(part, 1, 64) + s_qe[rowsel ? ki : kj];
            float pm   = fmaxf(m, lg);
            float corr = __expf(m - pm);       // first iter: exp(-huge) = 0
            float pe   = __expf(lg - pm);
            d = fmaf(d, corr, pe);
            m = pm;
            #pragma unroll
            for (int j = 0; j < 4; ++j) {
                uint2 w = vp[j];
                o[4 * j + 0] = fmaf(bflo(w.x), pe, o[4 * j + 0] * corr);
                o[4 * j + 1] = fmaf(bfhi(w.x), pe, o[4 * j + 1] * corr);
                o[4 * j + 2] = fmaf(bflo(w.y), pe, o[4 * j + 2] * corr);
                o[4 * j + 3] = fmaf(bfhi(w.y), pe, o[4 * j + 3] * corr);
            }
        }
    }

    // ---- write 16 channels ----
    float inv = 1.0f / d;
    float* op = out + (size_t)(b * 256 + g * 32 + h * 16) * 4096 + yy * 64 + xx;
    #pragma unroll
    for (int c = 0; c < 16; ++c)
        op[c * 4096] = o[c] * inv;
}

extern "C" void kernel_launch(void* const* d_in, const int* in_sizes, int n_in,
                              void* d_out, int out_size, void* d_ws, size_t ws_size,
                              hipStream_t stream) {
    const float* x       = (const float*)d_in[0];
    const float* wq      = (const float*)d_in[1];
    const float* wk      = (const float*)d_in[2];
    const float* wv      = (const float*)d_in[3];
    const float* row_emb = (const float*)d_in[4];
    const float* col_emb = (const float*)d_in[5];
    float* out = (float*)d_out;

    dim3 grid(4, 4, 32);   // (W/16, H/16, B*G)
    dim3 block(512);
    sasa_fused_kernel<<<grid, block, 0, stream>>>(x, wq, wk, wv, row_emb, col_emb, out);
}

// Round 10
// 82.997 us; speedup vs baseline: 3.6139x; 1.2961x over previous
//
#include <hip/hip_runtime.h>
#include <hip/hip_bf16.h>

// SASA local self-attention, fused, lane-paired channel-split.
// Round 9 (resubmit; container died): kill LDS bank conflicts —
//  (a) wave-uniform (kv,hh) in projection => weight reads broadcast (were 4-way same-bank)
//  (b) K/V stride 17 dwords (odd, coprime 32) => b32 reads spread <=2-way
// B=4, CIN=COUT=256, H=W=64, G=8, CG=32, K=7, PAD=3.
#define TS   16          // spatial tile (16x16 outputs per block)
#define HS   22          // halo tile side = TS + K-1
#define HP   484         // HS*HS
#define KDW  17          // dword stride per halo pixel (68B, odd => bank-spread)
#define KK   7
#define WSLOT 516        // padded weight slot (floats): bases at banks 0/4/8/12

__device__ __forceinline__ float bflo(unsigned u){ return __uint_as_float(u << 16); }
__device__ __forceinline__ float bfhi(unsigned u){ return __uint_as_float(u & 0xffff0000u); }
__device__ __forceinline__ unsigned bfpack(float a, float b){
    __hip_bfloat162 h2 = __float22bfloat162_rn(make_float2(a, b));
    union { __hip_bfloat162 h; unsigned u; } c; c.h = h2; return c.u;
}

__global__ __launch_bounds__(512, 4)
void sasa_fused_kernel(const float* __restrict__ x,
                       const float* __restrict__ wq,
                       const float* __restrict__ wk,
                       const float* __restrict__ wv,
                       const float* __restrict__ row_emb,
                       const float* __restrict__ col_emb,
                       float* __restrict__ out)
{
    __shared__ float s_w[4 * WSLOT];       // slots: 0,1 = wk(h0,h1) later wq; 2,3 = wv. Later: qe[256][7] aliases.
    __shared__ float s_emb[224];           // E[c][t] for this group (32 x 7)
    __shared__ unsigned s_ku[HP * KDW];
    __shared__ unsigned s_vu[HP * KDW];

    const int tid = threadIdx.x;
    const int bz  = blockIdx.z;
    const int b   = bz >> 3;
    const int g   = bz & 7;
    const int y0  = blockIdx.y * TS;
    const int x0  = blockIdx.x * TS;

    // ---- stage w_k, w_v (fp32) into padded slots + emb slice ----
    #pragma unroll
    for (int i = 0; i < 2; ++i) {
        int e   = tid + i * 512;           // [0,1024)
        int hh  = e >> 9;                  // which channel-half
        int idx = e & 511;                 // co_local*32 + ci
        s_w[hh * WSLOT + idx]       = wk[g * 1024 + e];
        s_w[(2 + hh) * WSLOT + idx] = wv[g * 1024 + e];
    }
    if (tid < 224) {
        int c = tid / KK, t = tid - c * KK;
        s_emb[tid] = (g < 4) ? row_emb[(g * 32 + c) * KK + t]
                             : col_emb[((g - 4) * 32 + c) * KK + t];
    }
    __syncthreads();

    const float* xg = x + (size_t)(b * 256 + g * 32) * 4096;

    // ---- halo K/V projection -> LDS (bf16 packed in u32).
    //      item = kv*968 + hh*484 + hp : (kv,hh) wave-uniform => weight reads broadcast. ----
    #pragma unroll 1
    for (int k = 0; k < 4; ++k) {
        const int it = k * 512 + tid;
        if (it < HP * 4) {
            const int kv = it / 968;
            const int r  = it - kv * 968;
            const int hh = r / HP;
            const int hp = r - hh * HP;
            const int hy = hp / HS, hx = hp - hy * HS;
            const int gy = y0 + hy - 3, gx = x0 + hx - 3;
            float acc[16];
            #pragma unroll
            for (int c = 0; c < 16; ++c) acc[c] = 0.f;
            if ((unsigned)gy < 64u && (unsigned)gx < 64u) {
                const float* xp = xg + gy * 64 + gx;
                const float* wb = s_w + (kv * 2 + hh) * WSLOT;
                #pragma unroll 4
                for (int ci = 0; ci < 32; ++ci) {
                    float xv = xp[ci * 4096];
                    #pragma unroll
                    for (int co = 0; co < 16; ++co)
                        acc[co] = fmaf(wb[co * 32 + ci], xv, acc[co]);
                }
            }
            unsigned* d32 = (kv ? s_vu : s_ku) + hp * KDW + hh * 8;
            #pragma unroll
            for (int j = 0; j < 8; ++j)
                d32[j] = bfpack(acc[2 * j], acc[2 * j + 1]);
        }
    }
    __syncthreads();

    // ---- reuse wk slots (0,1) for wq ----
    #pragma unroll
    for (int i = 0; i < 2; ++i) {
        int e   = tid + i * 512;
        int hh  = e >> 9;
        int idx = e & 511;
        s_w[hh * WSLOT + idx] = wq[g * 1024 + e];
    }
    __syncthreads();

    // ---- q projection: thread (p, h) owns 16 q channels ----
    const int p  = tid >> 1;
    const int h  = tid & 1;
    const int tx = p & 15, ty = p >> 4;
    const int yy = y0 + ty, xx = x0 + tx;
    float q[16];
    #pragma unroll
    for (int c = 0; c < 16; ++c) q[c] = 0.f;
    {
        const float* xp = xg + yy * 64 + xx;
        const float* wb = s_w + h * WSLOT;     // h=0/1 bases in different banks, broadcast
        #pragma unroll 4
        for (int ci = 0; ci < 32; ++ci) {
            float xv = xp[ci * 4096];
            #pragma unroll
            for (int co = 0; co < 16; ++co)
                q[co] = fmaf(wb[co * 32 + ci], xv, q[co]);
        }
    }

    // ---- qe[7] = q . emb (pair-combined); park per-pixel in LDS over dead wq slots ----
    float qe[KK];
    #pragma unroll
    for (int t = 0; t < KK; ++t) {
        float a = 0.f;
        #pragma unroll
        for (int c = 0; c < 16; ++c)
            a = fmaf(q[c], s_emb[(h * 16 + c) * KK + t], a);
        qe[t] = a;
    }
    #pragma unroll
    for (int t = 0; t < KK; ++t)
        qe[t] += __shfl_xor(qe[t], 1, 64);
    __syncthreads();                       // all wq reads complete before overwrite
    float* s_qe = s_w + p * KK;            // per-pixel 7-float slot (1792 <= 2064)
    if (h == 0) {
        #pragma unroll
        for (int t = 0; t < KK; ++t) s_qe[t] = qe[t];
    }
    // pair lanes are in the same wave: no barrier needed for readback

    // ---- online-softmax attention; o[16] per thread ----
    const int rowsel = (g < 4) ? 1 : 0;
    float m = -3.0e38f, d = 0.f;
    float o[16];
    #pragma unroll
    for (int c = 0; c < 16; ++c) o[c] = 0.f;

    #pragma unroll 1
    for (int ki = 0; ki < KK; ++ki) {
        const int hprow = (ty + ki) * HS + tx;
        #pragma unroll
        for (int kj = 0; kj < KK; ++kj) {
            const int hp = hprow + kj;
            const unsigned* kp = s_ku + hp * KDW + h * 8;
            const unsigned* vp = s_vu + hp * KDW + h * 8;
            float part = 0.f;
            #pragma unroll
            for (int jj = 0; jj < 8; ++jj) {
                unsigned w = kp[jj];
                part = fmaf(bflo(w), q[2 * jj + 0], part);
                part = fmaf(bfhi(w), q[2 * jj + 1], part);
            }
            float lg = part + __shfl_xor(part, 1, 64) + s_qe[rowsel ? ki : kj];
            float pm   = fmaxf(m, lg);
            float corr = __expf(m - pm);       // first iter: exp(-huge) = 0
            float pe   = __expf(lg - pm);
            d = fmaf(d, corr, pe);
            m = pm;
            #pragma unroll
            for (int jj = 0; jj < 8; ++jj) {
                unsigned w = vp[jj];
                o[2 * jj + 0] = fmaf(bflo(w), pe, o[2 * jj + 0] * corr);
                o[2 * jj + 1] = fmaf(bfhi(w), pe, o[2 * jj + 1] * corr);
            }
        }
    }

    // ---- write 16 channels ----
    float inv = 1.0f / d;
    float* op = out + (size_t)(b * 256 + g * 32 + h * 16) * 4096 + yy * 64 + xx;
    #pragma unroll
    for (int c = 0; c < 16; ++c)
        op[c * 4096] = o[c] * inv;
}

extern "C" void kernel_launch(void* const* d_in, const int* in_sizes, int n_in,
                              void* d_out, int out_size, void* d_ws, size_t ws_size,
                              hipStream_t stream) {
    const float* x       = (const float*)d_in[0];
    const float* wq      = (const float*)d_in[1];
    const float* wk      = (const float*)d_in[2];
    const float* wv      = (const float*)d_in[3];
    const float* row_emb = (const float*)d_in[4];
    const float* col_emb = (const float*)d_in[5];
    float* out = (float*)d_out;

    dim3 grid(4, 4, 32);   // (W/16, H/16, B*G)
    dim3 block(512);
    sasa_fused_kernel<<<grid, block, 0, stream>>>(x, wq, wk, wv, row_emb, col_emb, out);
}

// Round 12
// 61.666 us; speedup vs baseline: 4.8640x; 1.3459x over previous
//
#include <hip/hip_runtime.h>
#include <hip/hip_bf16.h>
#include <hip/hip_fp16.h>

// SASA local self-attention, fused. Round 12: packed-f16 math (compile fix of r11).
//  - K/V/weights in f16 pairs; v_dot2_f32_f16 for projections + K-dot (f32 accum)
//  - v_pk_fma_f16 (__hfma2) for PV accumulation
//  - K+V merged per projection item (x-halo redundancy 4x -> 2x)
//  - qe in registers (col groups); 1 hoisted LDS read/ki for row groups
// B=4, CIN=COUT=256, H=W=64, G=8, CG=32, K=7, PAD=3.
#define TS   16
#define HS   22
#define HP   484
#define KDW  17          // u32 stride per halo pixel (odd => bank-spread)
#define KK   7

typedef _Float16 h2 __attribute__((ext_vector_type(2)));
union U32H { unsigned u; h2 h; __half2 p; };

__device__ __forceinline__ h2 pkrtz(float a, float b) {
    auto r = __builtin_amdgcn_cvt_pkrtz(a, b);     // __fp16 vec2 on this clang
    union { decltype(r) i; h2 o; } c; c.i = r;     // same bits, retype
    return c.o;
}
__device__ __forceinline__ float dot2(h2 a, h2 b, float c) {
#if __has_builtin(__builtin_amdgcn_fdot2)
    return __builtin_amdgcn_fdot2(a, b, c, false);
#else
    return fmaf((float)a.x, (float)b.x, fmaf((float)a.y, (float)b.y, c));
#endif
}

__global__ __launch_bounds__(512, 4)
void sasa_fused_kernel(const float* __restrict__ x,
                       const float* __restrict__ wq,
                       const float* __restrict__ wk,
                       const float* __restrict__ wv,
                       const float* __restrict__ row_emb,
                       const float* __restrict__ col_emb,
                       float* __restrict__ out)
{
    __shared__ h2       s_w[1536];         // [m(k,v,q)*2+hh][cp 0..15][co 0..15], 6 KB
    __shared__ float    s_emb[224];        // E[c][t], 0.9 KB
    __shared__ float    s_qe[256 * KK];    // per-pixel qe slots (row groups), 7 KB
    __shared__ unsigned s_ku[HP * KDW];    // K halo, f16 pairs, 32.9 KB
    __shared__ unsigned s_vu[HP * KDW];    // V halo, f16 pairs, 32.9 KB

    const int tid = threadIdx.x;
    const int bz  = blockIdx.z;
    const int b   = bz >> 3;
    const int g   = bz & 7;
    const int y0  = blockIdx.y * TS;
    const int x0  = blockIdx.x * TS;

    // ---- stage all 3 weight matrices as f16 pairs + emb slice ----
    {
        // t -> co_g = t>>4 (0..31), cp = t&15 ; float2 element index == t
        const int cp  = tid & 15;
        const int cog = tid >> 4;
        const int hh  = cog >> 4;
        const int co  = cog & 15;
        const int di  = (hh * 16 + cp) * 16 + co;   // within matrix: hh*256 + cp*16 + co
        const float2* wk2 = (const float2*)(wk + g * 1024);
        const float2* wv2 = (const float2*)(wv + g * 1024);
        const float2* wq2 = (const float2*)(wq + g * 1024);
        float2 a = wk2[tid]; s_w[di]        = pkrtz(a.x, a.y);
        float2 v = wv2[tid]; s_w[512 + di]  = pkrtz(v.x, v.y);
        float2 q = wq2[tid]; s_w[1024 + di] = pkrtz(q.x, q.y);
    }
    if (tid < 224) {
        int c = tid / KK, t = tid - c * KK;
        s_emb[tid] = (g < 4) ? row_emb[(g * 32 + c) * KK + t]
                             : col_emb[((g - 4) * 32 + c) * KK + t];
    }
    __syncthreads();

    const float* xg = x + (size_t)(b * 256 + g * 32) * 4096;

    // ---- halo K+V projection -> LDS. Item = (hh, hp): 32 f32 accs via dot2. ----
    #pragma unroll 1
    for (int k = 0; k < 2; ++k) {
        const int it = k * 512 + tid;
        if (it < 2 * HP) {
            const int hh = (it >= HP) ? 1 : 0;
            const int hp = it - (hh ? HP : 0);
            const int hy = hp / HS, hx = hp - hy * HS;
            const int gy = y0 + hy - 3, gx = x0 + hx - 3;
            float accK[16], accV[16];
            #pragma unroll
            for (int c = 0; c < 16; ++c) { accK[c] = 0.f; accV[c] = 0.f; }
            if ((unsigned)gy < 64u && (unsigned)gx < 64u) {
                const float* xp = xg + gy * 64 + gx;
                h2 xv2[16];
                #pragma unroll
                for (int cp = 0; cp < 16; ++cp)
                    xv2[cp] = pkrtz(xp[(2 * cp) * 4096], xp[(2 * cp + 1) * 4096]);
                const h2* wkp = s_w + hh * 256;          // m=0
                const h2* wvp = s_w + 512 + hh * 256;    // m=1
                #pragma unroll
                for (int cp = 0; cp < 16; ++cp) {
                    h2 xv = xv2[cp];
                    #pragma unroll
                    for (int co = 0; co < 16; ++co) {
                        accK[co] = dot2(wkp[cp * 16 + co], xv, accK[co]);
                        accV[co] = dot2(wvp[cp * 16 + co], xv, accV[co]);
                    }
                }
            }
            unsigned* dk = s_ku + hp * KDW + hh * 8;
            unsigned* dv = s_vu + hp * KDW + hh * 8;
            #pragma unroll
            for (int j = 0; j < 8; ++j) {
                U32H ck; ck.h = pkrtz(accK[2 * j], accK[2 * j + 1]); dk[j] = ck.u;
                U32H cv; cv.h = pkrtz(accV[2 * j], accV[2 * j + 1]); dv[j] = cv.u;
            }
        }
    }

    // ---- q projection: thread (p, h) owns 16 q channels (dot2, f32 accum) ----
    const int p  = tid >> 1;
    const int h  = tid & 1;
    const int tx = p & 15, ty = p >> 4;
    const int yy = y0 + ty, xx = x0 + tx;
    float accQ[16];
    #pragma unroll
    for (int c = 0; c < 16; ++c) accQ[c] = 0.f;
    {
        const float* xp = xg + yy * 64 + xx;
        h2 xv2[16];
        #pragma unroll
        for (int cp = 0; cp < 16; ++cp)
            xv2[cp] = pkrtz(xp[(2 * cp) * 4096], xp[(2 * cp + 1) * 4096]);
        const h2* wqp = s_w + 1024 + h * 256;            // m=2, 2-addr broadcast
        #pragma unroll
        for (int cp = 0; cp < 16; ++cp) {
            h2 xv = xv2[cp];
            #pragma unroll
            for (int co = 0; co < 16; ++co)
                accQ[co] = dot2(wqp[cp * 16 + co], xv, accQ[co]);
        }
    }

    // ---- qe[7] = q . emb (pair-combined via shfl); park for row groups ----
    float qe[KK];
    #pragma unroll
    for (int t = 0; t < KK; ++t) {
        float a = 0.f;
        #pragma unroll
        for (int c = 0; c < 16; ++c)
            a = fmaf(accQ[c], s_emb[(h * 16 + c) * KK + t], a);
        qe[t] = a;
    }
    #pragma unroll
    for (int t = 0; t < KK; ++t)
        qe[t] += __shfl_xor(qe[t], 1, 64);
    if (h == 0) {
        #pragma unroll
        for (int t = 0; t < KK; ++t) s_qe[p * KK + t] = qe[t];
    }
    // (pair lanes are in the same wave; same-wave LDS ordering makes readback safe)

    // ---- pack q to f16 pairs ----
    h2 q2[8];
    #pragma unroll
    for (int j = 0; j < 8; ++j) q2[j] = pkrtz(accQ[2 * j], accQ[2 * j + 1]);

    __syncthreads();   // s_ku / s_vu complete

    // ---- online-softmax attention; o in packed f16 (v_pk_fma_f16) ----
    const int rowsel = (g < 4) ? 1 : 0;
    float m = -3.0e38f, d = 0.f;
    __half2 o2[8];
    #pragma unroll
    for (int j = 0; j < 8; ++j) o2[j] = __float2half2_rn(0.f);

    #pragma unroll 1
    for (int ki = 0; ki < KK; ++ki) {
        const int hprow = (ty + ki) * HS + tx;
        const float addk = s_qe[p * KK + ki];   // hoisted: 1 read per ki (row groups)
        #pragma unroll
        for (int kj = 0; kj < KK; ++kj) {
            const int hp = hprow + kj;
            const unsigned* kp = s_ku + hp * KDW + h * 8;
            const unsigned* vp = s_vu + hp * KDW + h * 8;
            float part = 0.f;
            #pragma unroll
            for (int jj = 0; jj < 8; ++jj) {
                U32H w; w.u = kp[jj];
                part = dot2(w.h, q2[jj], part);
            }
            float lg = part + __shfl_xor(part, 1, 64) + (rowsel ? addk : qe[kj]);
            float pm   = fmaxf(m, lg);
            float corr = __expf(m - pm);        // first iter: exp(-huge) = 0
            float pe   = __expf(lg - pm);
            d = fmaf(d, corr, pe);
            m = pm;
            __half2 pe2   = __float2half2_rn(pe);
            __half2 corr2 = __float2half2_rn(corr);
            #pragma unroll
            for (int jj = 0; jj < 8; ++jj) {
                U32H w; w.u = vp[jj];
                o2[jj] = __hfma2(w.p, pe2, __hmul2(o2[jj], corr2));
            }
        }
    }

    // ---- write 16 channels ----
    float inv = 1.0f / d;
    float* op = out + (size_t)(b * 256 + g * 32 + h * 16) * 4096 + yy * 64 + xx;
    #pragma unroll
    for (int j = 0; j < 8; ++j) {
        float2 f = __half22float2(o2[j]);
        op[(2 * j) * 4096]     = f.x * inv;
        op[(2 * j + 1) * 4096] = f.y * inv;
    }
}

extern "C" void kernel_launch(void* const* d_in, const int* in_sizes, int n_in,
                              void* d_out, int out_size, void* d_ws, size_t ws_size,
                              hipStream_t stream) {
    const float* x       = (const float*)d_in[0];
    const float* wq      = (const float*)d_in[1];
    const float* wk      = (const float*)d_in[2];
    const float* wv      = (const float*)d_in[3];
    const float* row_emb = (const float*)d_in[4];
    const float* col_emb = (const float*)d_in[5];
    float* out = (float*)d_out;

    dim3 grid(4, 4, 32);   // (W/16, H/16, B*G)
    dim3 block(512);
    sasa_fused_kernel<<<grid, block, 0, stream>>>(x, wq, wk, wv, row_emb, col_emb, out);
}

// Round 13
// 59.290 us; speedup vs baseline: 5.0589x; 1.0401x over previous
//
#include <hip/hip_runtime.h>
#include <hip/hip_bf16.h>
#include <hip/hip_fp16.h>

// SASA local self-attention, fused. Round 13: two-pass register softmax.
//  - Phase A: all 49 logits -> lg[] regs (independent shfl/dots, pipelined)
//  - Phase B: tree max, 49 independent expf (no corr), tree sum, pure-fma PV
//  - qe statically indexed (full unroll) -> s_qe LDS eliminated
// B=4, CIN=COUT=256, H=W=64, G=8, CG=32, K=7, PAD=3.
#define TS   16
#define HS   22
#define HP   484
#define KDW  17          // u32 stride per halo pixel (odd => bank-spread)
#define KK   7
#define K2   49

typedef _Float16 h2 __attribute__((ext_vector_type(2)));
union U32H { unsigned u; h2 h; __half2 p; };

__device__ __forceinline__ h2 pkrtz(float a, float b) {
    auto r = __builtin_amdgcn_cvt_pkrtz(a, b);     // __fp16 vec2 on this clang
    union { decltype(r) i; h2 o; } c; c.i = r;     // same bits, retype
    return c.o;
}
__device__ __forceinline__ float dot2(h2 a, h2 b, float c) {
#if __has_builtin(__builtin_amdgcn_fdot2)
    return __builtin_amdgcn_fdot2(a, b, c, false);
#else
    return fmaf((float)a.x, (float)b.x, fmaf((float)a.y, (float)b.y, c));
#endif
}

__global__ __launch_bounds__(512, 4)
void sasa_fused_kernel(const float* __restrict__ x,
                       const float* __restrict__ wq,
                       const float* __restrict__ wk,
                       const float* __restrict__ wv,
                       const float* __restrict__ row_emb,
                       const float* __restrict__ col_emb,
                       float* __restrict__ out)
{
    __shared__ h2       s_w[1536];         // [m(k,v,q)*2+hh][cp][co], 6 KB
    __shared__ float    s_emb[224];        // E[c][t], 0.9 KB
    __shared__ unsigned s_ku[HP * KDW];    // K halo, f16 pairs, 32.9 KB
    __shared__ unsigned s_vu[HP * KDW];    // V halo, f16 pairs, 32.9 KB

    const int tid = threadIdx.x;
    const int bz  = blockIdx.z;
    const int b   = bz >> 3;
    const int g   = bz & 7;
    const int y0  = blockIdx.y * TS;
    const int x0  = blockIdx.x * TS;

    // ---- stage all 3 weight matrices as f16 pairs + emb slice ----
    {
        const int cp  = tid & 15;
        const int cog = tid >> 4;
        const int hh  = cog >> 4;
        const int co  = cog & 15;
        const int di  = (hh * 16 + cp) * 16 + co;
        const float2* wk2 = (const float2*)(wk + g * 1024);
        const float2* wv2 = (const float2*)(wv + g * 1024);
        const float2* wq2 = (const float2*)(wq + g * 1024);
        float2 a = wk2[tid]; s_w[di]        = pkrtz(a.x, a.y);
        float2 v = wv2[tid]; s_w[512 + di]  = pkrtz(v.x, v.y);
        float2 q = wq2[tid]; s_w[1024 + di] = pkrtz(q.x, q.y);
    }
    if (tid < 224) {
        int c = tid / KK, t = tid - c * KK;
        s_emb[tid] = (g < 4) ? row_emb[(g * 32 + c) * KK + t]
                             : col_emb[((g - 4) * 32 + c) * KK + t];
    }
    __syncthreads();

    const float* xg = x + (size_t)(b * 256 + g * 32) * 4096;

    // ---- halo K+V projection -> LDS. Item = (hh, hp): 32 f32 accs via dot2. ----
    #pragma unroll 1
    for (int k = 0; k < 2; ++k) {
        const int it = k * 512 + tid;
        if (it < 2 * HP) {
            const int hh = (it >= HP) ? 1 : 0;
            const int hp = it - (hh ? HP : 0);
            const int hy = hp / HS, hx = hp - hy * HS;
            const int gy = y0 + hy - 3, gx = x0 + hx - 3;
            float accK[16], accV[16];
            #pragma unroll
            for (int c = 0; c < 16; ++c) { accK[c] = 0.f; accV[c] = 0.f; }
            if ((unsigned)gy < 64u && (unsigned)gx < 64u) {
                const float* xp = xg + gy * 64 + gx;
                h2 xv2[16];
                #pragma unroll
                for (int cp = 0; cp < 16; ++cp)
                    xv2[cp] = pkrtz(xp[(2 * cp) * 4096], xp[(2 * cp + 1) * 4096]);
                const h2* wkp = s_w + hh * 256;
                const h2* wvp = s_w + 512 + hh * 256;
                #pragma unroll
                for (int cp = 0; cp < 16; ++cp) {
                    h2 xv = xv2[cp];
                    #pragma unroll
                    for (int co = 0; co < 16; ++co) {
                        accK[co] = dot2(wkp[cp * 16 + co], xv, accK[co]);
                        accV[co] = dot2(wvp[cp * 16 + co], xv, accV[co]);
                    }
                }
            }
            unsigned* dk = s_ku + hp * KDW + hh * 8;
            unsigned* dv = s_vu + hp * KDW + hh * 8;
            #pragma unroll
            for (int j = 0; j < 8; ++j) {
                U32H ck; ck.h = pkrtz(accK[2 * j], accK[2 * j + 1]); dk[j] = ck.u;
                U32H cv; cv.h = pkrtz(accV[2 * j], accV[2 * j + 1]); dv[j] = cv.u;
            }
        }
    }

    // ---- q projection: thread (p, h) owns 16 q channels ----
    const int p  = tid >> 1;
    const int h  = tid & 1;
    const int tx = p & 15, ty = p >> 4;
    const int yy = y0 + ty, xx = x0 + tx;
    float accQ[16];
    #pragma unroll
    for (int c = 0; c < 16; ++c) accQ[c] = 0.f;
    {
        const float* xp = xg + yy * 64 + xx;
        h2 xv2[16];
        #pragma unroll
        for (int cp = 0; cp < 16; ++cp)
            xv2[cp] = pkrtz(xp[(2 * cp) * 4096], xp[(2 * cp + 1) * 4096]);
        const h2* wqp = s_w + 1024 + h * 256;
        #pragma unroll
        for (int cp = 0; cp < 16; ++cp) {
            h2 xv = xv2[cp];
            #pragma unroll
            for (int co = 0; co < 16; ++co)
                accQ[co] = dot2(wqp[cp * 16 + co], xv, accQ[co]);
        }
    }

    // ---- qe[7] = q . emb, pair-combined (both lanes end with the full value) ----
    float qe[KK];
    #pragma unroll
    for (int t = 0; t < KK; ++t) {
        float a = 0.f;
        #pragma unroll
        for (int c = 0; c < 16; ++c)
            a = fmaf(accQ[c], s_emb[(h * 16 + c) * KK + t], a);
        qe[t] = a;
    }
    #pragma unroll
    for (int t = 0; t < KK; ++t)
        qe[t] += __shfl_xor(qe[t], 1, 64);

    // ---- pack q to f16 pairs ----
    h2 q2[8];
    #pragma unroll
    for (int j = 0; j < 8; ++j) q2[j] = pkrtz(accQ[2 * j], accQ[2 * j + 1]);

    __syncthreads();   // s_ku / s_vu complete

    const int rowsel = (g < 4) ? 1 : 0;

    // ---- Phase A: all 49 logits (independent; shfl/dots pipeline) ----
    float lg[K2];
    #pragma unroll
    for (int ki = 0; ki < KK; ++ki) {
        #pragma unroll
        for (int kj = 0; kj < KK; ++kj) {
            const int hp = (ty + ki) * HS + tx + kj;
            const unsigned* kp = s_ku + hp * KDW + h * 8;
            float part = 0.f;
            #pragma unroll
            for (int jj = 0; jj < 8; ++jj) {
                U32H w; w.u = kp[jj];
                part = dot2(w.h, q2[jj], part);
            }
            lg[ki * KK + kj] = part + __shfl_xor(part, 1, 64)
                             + (rowsel ? qe[ki] : qe[kj]);
        }
    }

    // ---- Phase B: tree max, independent exps, tree sum ----
    float m0 = lg[0], m1 = lg[1], m2 = lg[2], m3 = lg[3];
    #pragma unroll
    for (int t = 4; t < 48; t += 4) {
        m0 = fmaxf(m0, lg[t]);
        m1 = fmaxf(m1, lg[t + 1]);
        m2 = fmaxf(m2, lg[t + 2]);
        m3 = fmaxf(m3, lg[t + 3]);
    }
    const float mx = fmaxf(fmaxf(m0, m1), fmaxf(m2, fmaxf(m3, lg[48])));

    float s0 = 0.f, s1 = 0.f, s2 = 0.f, s3 = 0.f;
    #pragma unroll
    for (int t = 0; t < K2; ++t) {
        float pe = __expf(lg[t] - mx);
        lg[t] = pe;
        if ((t & 3) == 0) s0 += pe;
        else if ((t & 3) == 1) s1 += pe;
        else if ((t & 3) == 2) s2 += pe;
        else s3 += pe;
    }
    const float s = (s0 + s1) + (s2 + s3);

    // ---- PV: pure f16 fma accumulation (8 independent chains) ----
    __half2 o2[8];
    #pragma unroll
    for (int j = 0; j < 8; ++j) o2[j] = __float2half2_rn(0.f);

    #pragma unroll
    for (int ki = 0; ki < KK; ++ki) {
        #pragma unroll
        for (int kj = 0; kj < KK; ++kj) {
            const int hp = (ty + ki) * HS + tx + kj;
            const unsigned* vp = s_vu + hp * KDW + h * 8;
            const __half2 pe2 = __float2half2_rn(lg[ki * KK + kj]);
            #pragma unroll
            for (int jj = 0; jj < 8; ++jj) {
                U32H w; w.u = vp[jj];
                o2[jj] = __hfma2(w.p, pe2, o2[jj]);
            }
        }
    }

    // ---- write 16 channels ----
    const float inv = 1.0f / s;
    float* op = out + (size_t)(b * 256 + g * 32 + h * 16) * 4096 + yy * 64 + xx;
    #pragma unroll
    for (int j = 0; j < 8; ++j) {
        float2 f = __half22float2(o2[j]);
        op[(2 * j) * 4096]     = f.x * inv;
        op[(2 * j + 1) * 4096] = f.y * inv;
    }
}

extern "C" void kernel_launch(void* const* d_in, const int* in_sizes, int n_in,
                              void* d_out, int out_size, void* d_ws, size_t ws_size,
                              hipStream_t stream) {
    const float* x       = (const float*)d_in[0];
    const float* wq      = (const float*)d_in[1];
    const float* wk      = (const float*)d_in[2];
    const float* wv      = (const float*)d_in[3];
    const float* row_emb = (const float*)d_in[4];
    const float* col_emb = (const float*)d_in[5];
    float* out = (float*)d_out;

    dim3 grid(4, 4, 32);   // (W/16, H/16, B*G)
    dim3 block(512);
    sasa_fused_kernel<<<grid, block, 0, stream>>>(x, wq, wk, wv, row_emb, col_emb, out);
}

// Round 14
// 58.859 us; speedup vs baseline: 5.0960x; 1.0073x over previous
//
#include <hip/hip_runtime.h>
#include <hip/hip_bf16.h>
#include <hip/hip_fp16.h>

// SASA local self-attention, fused. Round 14: LDS-pipe attack (wider LDS ops).
//  - KDW 18: attention K/V via ds_read_b64 (784 -> 392 LDS ops/thread)
//  - weight rows via ds_read_b128 broadcast (1280 -> 320)
//  - K/V stores as uint2
// B=4, CIN=COUT=256, H=W=64, G=8, CG=32, K=7, PAD=3.
#define TS   16
#define HS   22
#define HP   484
#define KDW  18          // u32 stride per halo pixel (72B: 8B-aligned, ~2-way max on b64)
#define KK   7
#define K2   49

typedef _Float16 h2 __attribute__((ext_vector_type(2)));
union U32H { unsigned u; h2 h; __half2 p; };

__device__ __forceinline__ h2 pkrtz(float a, float b) {
    auto r = __builtin_amdgcn_cvt_pkrtz(a, b);     // __fp16 vec2 on this clang
    union { decltype(r) i; h2 o; } c; c.i = r;     // same bits, retype
    return c.o;
}
__device__ __forceinline__ float dot2(h2 a, h2 b, float c) {
#if __has_builtin(__builtin_amdgcn_fdot2)
    return __builtin_amdgcn_fdot2(a, b, c, false);
#else
    return fmaf((float)a.x, (float)b.x, fmaf((float)a.y, (float)b.y, c));
#endif
}
__device__ __forceinline__ float dot2u(unsigned wu, h2 b, float c) {
    U32H w; w.u = wu; return dot2(w.h, b, c);
}

__global__ __launch_bounds__(512, 4)
void sasa_fused_kernel(const float* __restrict__ x,
                       const float* __restrict__ wq,
                       const float* __restrict__ wk,
                       const float* __restrict__ wv,
                       const float* __restrict__ row_emb,
                       const float* __restrict__ col_emb,
                       float* __restrict__ out)
{
    __shared__ h2       s_w[1536];         // [m(k,v,q)*2+hh][cp][co], 6 KB, rows 16B-aligned
    __shared__ float    s_emb[224];        // E[c][t], 0.9 KB
    __shared__ unsigned s_ku[HP * KDW];    // K halo, f16 pairs, 34.0 KB
    __shared__ unsigned s_vu[HP * KDW];    // V halo, f16 pairs, 34.0 KB

    const int tid = threadIdx.x;
    const int bz  = blockIdx.z;
    const int b   = bz >> 3;
    const int g   = bz & 7;
    const int y0  = blockIdx.y * TS;
    const int x0  = blockIdx.x * TS;

    // ---- stage all 3 weight matrices as f16 pairs + emb slice ----
    {
        const int cp  = tid & 15;
        const int cog = tid >> 4;
        const int hh  = cog >> 4;
        const int co  = cog & 15;
        const int di  = (hh * 16 + cp) * 16 + co;
        const float2* wk2 = (const float2*)(wk + g * 1024);
        const float2* wv2 = (const float2*)(wv + g * 1024);
        const float2* wq2 = (const float2*)(wq + g * 1024);
        float2 a = wk2[tid]; s_w[di]        = pkrtz(a.x, a.y);
        float2 v = wv2[tid]; s_w[512 + di]  = pkrtz(v.x, v.y);
        float2 q = wq2[tid]; s_w[1024 + di] = pkrtz(q.x, q.y);
    }
    if (tid < 224) {
        int c = tid / KK, t = tid - c * KK;
        s_emb[tid] = (g < 4) ? row_emb[(g * 32 + c) * KK + t]
                             : col_emb[((g - 4) * 32 + c) * KK + t];
    }
    __syncthreads();

    const float* xg = x + (size_t)(b * 256 + g * 32) * 4096;

    // ---- halo K+V projection -> LDS. Item = (hh, hp): 32 f32 accs via dot2. ----
    #pragma unroll 1
    for (int k = 0; k < 2; ++k) {
        const int it = k * 512 + tid;
        if (it < 2 * HP) {
            const int hh = (it >= HP) ? 1 : 0;
            const int hp = it - (hh ? HP : 0);
            const int hy = hp / HS, hx = hp - hy * HS;
            const int gy = y0 + hy - 3, gx = x0 + hx - 3;
            float accK[16], accV[16];
            #pragma unroll
            for (int c = 0; c < 16; ++c) { accK[c] = 0.f; accV[c] = 0.f; }
            if ((unsigned)gy < 64u && (unsigned)gx < 64u) {
                const float* xp = xg + gy * 64 + gx;
                h2 xv2[16];
                #pragma unroll
                for (int cp = 0; cp < 16; ++cp)
                    xv2[cp] = pkrtz(xp[(2 * cp) * 4096], xp[(2 * cp + 1) * 4096]);
                const h2* wkp = s_w + hh * 256;          // 16B-aligned rows
                const h2* wvp = s_w + 512 + hh * 256;
                #pragma unroll
                for (int cp = 0; cp < 16; ++cp) {
                    h2 xv = xv2[cp];
                    const uint4* wkr = (const uint4*)(wkp + cp * 16);
                    const uint4* wvr = (const uint4*)(wvp + cp * 16);
                    uint4 kw[4] = { wkr[0], wkr[1], wkr[2], wkr[3] };
                    uint4 vw[4] = { wvr[0], wvr[1], wvr[2], wvr[3] };
                    const unsigned* kwu = (const unsigned*)kw;
                    const unsigned* vwu = (const unsigned*)vw;
                    #pragma unroll
                    for (int co = 0; co < 16; ++co) {
                        accK[co] = dot2u(kwu[co], xv, accK[co]);
                        accV[co] = dot2u(vwu[co], xv, accV[co]);
                    }
                }
            }
            unsigned* dk = s_ku + hp * KDW + hh * 8;     // byte ofs: hp*72+hh*32, 8B-aligned
            unsigned* dv = s_vu + hp * KDW + hh * 8;
            #pragma unroll
            for (int j = 0; j < 4; ++j) {
                U32H a0, a1, b0, b1;
                a0.h = pkrtz(accK[4 * j],     accK[4 * j + 1]);
                a1.h = pkrtz(accK[4 * j + 2], accK[4 * j + 3]);
                b0.h = pkrtz(accV[4 * j],     accV[4 * j + 1]);
                b1.h = pkrtz(accV[4 * j + 2], accV[4 * j + 3]);
                ((uint2*)dk)[j] = make_uint2(a0.u, a1.u);
                ((uint2*)dv)[j] = make_uint2(b0.u, b1.u);
            }
        }
    }

    // ---- q projection: thread (p, h) owns 16 q channels ----
    const int p  = tid >> 1;
    const int h  = tid & 1;
    const int tx = p & 15, ty = p >> 4;
    const int yy = y0 + ty, xx = x0 + tx;
    float accQ[16];
    #pragma unroll
    for (int c = 0; c < 16; ++c) accQ[c] = 0.f;
    {
        const float* xp = xg + yy * 64 + xx;
        h2 xv2[16];
        #pragma unroll
        for (int cp = 0; cp < 16; ++cp)
            xv2[cp] = pkrtz(xp[(2 * cp) * 4096], xp[(2 * cp + 1) * 4096]);
        const h2* wqp = s_w + 1024 + h * 256;
        #pragma unroll
        for (int cp = 0; cp < 16; ++cp) {
            h2 xv = xv2[cp];
            const uint4* wqr = (const uint4*)(wqp + cp * 16);
            uint4 qw[4] = { wqr[0], wqr[1], wqr[2], wqr[3] };
            const unsigned* qwu = (const unsigned*)qw;
            #pragma unroll
            for (int co = 0; co < 16; ++co)
                accQ[co] = dot2u(qwu[co], xv, accQ[co]);
        }
    }

    // ---- qe[7] = q . emb, pair-combined (both lanes end with the full value) ----
    float qe[KK];
    #pragma unroll
    for (int t = 0; t < KK; ++t) {
        float a = 0.f;
        #pragma unroll
        for (int c = 0; c < 16; ++c)
            a = fmaf(accQ[c], s_emb[(h * 16 + c) * KK + t], a);
        qe[t] = a;
    }
    #pragma unroll
    for (int t = 0; t < KK; ++t)
        qe[t] += __shfl_xor(qe[t], 1, 64);

    // ---- pack q to f16 pairs ----
    h2 q2[8];
    #pragma unroll
    for (int j = 0; j < 8; ++j) q2[j] = pkrtz(accQ[2 * j], accQ[2 * j + 1]);

    __syncthreads();   // s_ku / s_vu complete

    const int rowsel = (g < 4) ? 1 : 0;

    // ---- Phase A: all 49 logits (b64 K reads; independent, pipelined) ----
    float lg[K2];
    const unsigned* kb = s_ku + h * 8;
    #pragma unroll
    for (int ki = 0; ki < KK; ++ki) {
        #pragma unroll
        for (int kj = 0; kj < KK; ++kj) {
            const int hp = (ty + ki) * HS + tx + kj;
            const uint2* kp = (const uint2*)(kb + hp * KDW);
            uint2 w0 = kp[0], w1 = kp[1], w2 = kp[2], w3 = kp[3];
            float part = 0.f;
            part = dot2u(w0.x, q2[0], part);
            part = dot2u(w0.y, q2[1], part);
            part = dot2u(w1.x, q2[2], part);
            part = dot2u(w1.y, q2[3], part);
            part = dot2u(w2.x, q2[4], part);
            part = dot2u(w2.y, q2[5], part);
            part = dot2u(w3.x, q2[6], part);
            part = dot2u(w3.y, q2[7], part);
            lg[ki * KK + kj] = part + __shfl_xor(part, 1, 64)
                             + (rowsel ? qe[ki] : qe[kj]);
        }
    }

    // ---- Phase B: tree max, independent exps, tree sum ----
    float m0 = lg[0], m1 = lg[1], m2 = lg[2], m3 = lg[3];
    #pragma unroll
    for (int t = 4; t < 48; t += 4) {
        m0 = fmaxf(m0, lg[t]);
        m1 = fmaxf(m1, lg[t + 1]);
        m2 = fmaxf(m2, lg[t + 2]);
        m3 = fmaxf(m3, lg[t + 3]);
    }
    const float mx = fmaxf(fmaxf(m0, m1), fmaxf(m2, fmaxf(m3, lg[48])));

    float s0 = 0.f, s1 = 0.f, s2 = 0.f, s3 = 0.f;
    #pragma unroll
    for (int t = 0; t < K2; ++t) {
        float pe = __expf(lg[t] - mx);
        lg[t] = pe;
        if ((t & 3) == 0) s0 += pe;
        else if ((t & 3) == 1) s1 += pe;
        else if ((t & 3) == 2) s2 += pe;
        else s3 += pe;
    }
    const float s = (s0 + s1) + (s2 + s3);

    // ---- PV: b64 V reads, pure f16 fma accumulation ----
    __half2 o2[8];
    #pragma unroll
    for (int j = 0; j < 8; ++j) o2[j] = __float2half2_rn(0.f);

    const unsigned* vb = s_vu + h * 8;
    #pragma unroll
    for (int ki = 0; ki < KK; ++ki) {
        #pragma unroll
        for (int kj = 0; kj < KK; ++kj) {
            const int hp = (ty + ki) * HS + tx + kj;
            const uint2* vp = (const uint2*)(vb + hp * KDW);
            uint2 w0 = vp[0], w1 = vp[1], w2 = vp[2], w3 = vp[3];
            const __half2 pe2 = __float2half2_rn(lg[ki * KK + kj]);
            U32H c0, c1, c2, c3, c4, c5, c6, c7;
            c0.u = w0.x; c1.u = w0.y; c2.u = w1.x; c3.u = w1.y;
            c4.u = w2.x; c5.u = w2.y; c6.u = w3.x; c7.u = w3.y;
            o2[0] = __hfma2(c0.p, pe2, o2[0]);
            o2[1] = __hfma2(c1.p, pe2, o2[1]);
            o2[2] = __hfma2(c2.p, pe2, o2[2]);
            o2[3] = __hfma2(c3.p, pe2, o2[3]);
            o2[4] = __hfma2(c4.p, pe2, o2[4]);
            o2[5] = __hfma2(c5.p, pe2, o2[5]);
            o2[6] = __hfma2(c6.p, pe2, o2[6]);
            o2[7] = __hfma2(c7.p, pe2, o2[7]);
        }
    }

    // ---- write 16 channels ----
    const float inv = 1.0f / s;
    float* op = out + (size_t)(b * 256 + g * 32 + h * 16) * 4096 + yy * 64 + xx;
    #pragma unroll
    for (int j = 0; j < 8; ++j) {
        float2 f = __half22float2(o2[j]);
        op[(2 * j) * 4096]     = f.x * inv;
        op[(2 * j + 1) * 4096] = f.y * inv;
    }
}

extern "C" void kernel_launch(void* const* d_in, const int* in_sizes, int n_in,
                              void* d_out, int out_size, void* d_ws, size_t ws_size,
                              hipStream_t stream) {
    const float* x       = (const float*)d_in[0];
    const float* wq      = (const float*)d_in[1];
    const float* wk      = (const float*)d_in[2];
    const float* wv      = (const float*)d_in[3];
    const float* row_emb = (const float*)d_in[4];
    const float* col_emb = (const float*)d_in[5];
    float* out = (float*)d_out;

    dim3 grid(4, 4, 32);   // (W/16, H/16, B*G)
    dim3 block(512);
    sasa_fused_kernel<<<grid, block, 0, stream>>>(x, wq, wk, wv, row_emb, col_emb, out);
}

// Round 15
// 51.441 us; speedup vs baseline: 5.8308x; 1.1442x over previous
//
#include <hip/hip_runtime.h>
#include <hip/hip_bf16.h>
#include <hip/hip_fp16.h>

// SASA local self-attention, fused. Round 15: latency attack.
//  - XCD-bijective block swizzle: all 16 tiles of a (b,g) x-slice on one XCD
//    (4 slices x 512KB = 2MB per XCD L2) -> halo re-reads hit L2, FETCH ~4x down
//  - projection x loads (both items) pre-issued before weight staging: one
//    exposed memory round trip instead of three
// B=4, CIN=COUT=256, H=W=64, G=8, CG=32, K=7, PAD=3.
#define TS   16
#define HS   22
#define HP   484
#define KDW  18          // u32 stride per halo pixel (72B: 8B-aligned, ~2-way max on b64)
#define KK   7
#define K2   49

typedef _Float16 h2 __attribute__((ext_vector_type(2)));
union U32H { unsigned u; h2 h; __half2 p; };

__device__ __forceinline__ h2 pkrtz(float a, float b) {
    auto r = __builtin_amdgcn_cvt_pkrtz(a, b);     // __fp16 vec2 on this clang
    union { decltype(r) i; h2 o; } c; c.i = r;     // same bits, retype
    return c.o;
}
__device__ __forceinline__ float dot2(h2 a, h2 b, float c) {
#if __has_builtin(__builtin_amdgcn_fdot2)
    return __builtin_amdgcn_fdot2(a, b, c, false);
#else
    return fmaf((float)a.x, (float)b.x, fmaf((float)a.y, (float)b.y, c));
#endif
}
__device__ __forceinline__ float dot2u(unsigned wu, h2 b, float c) {
    U32H w; w.u = wu; return dot2(w.h, b, c);
}

__global__ __launch_bounds__(512, 4)
void sasa_fused_kernel(const float* __restrict__ x,
                       const float* __restrict__ wq,
                       const float* __restrict__ wk,
                       const float* __restrict__ wv,
                       const float* __restrict__ row_emb,
                       const float* __restrict__ col_emb,
                       float* __restrict__ out)
{
    __shared__ h2       s_w[1536];         // [m(k,v,q)*2+hh][cp][co], 6 KB, rows 16B-aligned
    __shared__ float    s_emb[224];        // E[c][t], 0.9 KB
    __shared__ unsigned s_ku[HP * KDW];    // K halo, f16 pairs, 34.8 KB
    __shared__ unsigned s_vu[HP * KDW];    // V halo, f16 pairs, 34.8 KB

    const int tid = threadIdx.x;

    // ---- XCD-bijective swizzle: 16 spatial tiles of each (b,g) share an XCD ----
    const int lin  = blockIdx.x + (blockIdx.y << 2) + (blockIdx.z << 4); // [0,512)
    const int xcd  = lin & 7;
    const int slot = lin >> 3;               // [0,64) per xcd
    const int zg   = xcd + ((slot >> 4) << 3);   // 4 z-groups per xcd
    const int sp   = slot & 15;
    const int b    = zg >> 3;
    const int g    = zg & 7;
    const int y0   = (sp >> 2) * TS;
    const int x0   = (sp & 3) * TS;

    const float* xg = x + (size_t)(b * 256 + g * 32) * 4096;

    // ---- pre-issue projection x loads (both items) ----
    // item0: hh = tid>=484, hp = tid - hh*484 ; item1: hh=1, hp = tid+28 (valid tid<456)
    const int hh0 = (tid >= HP) ? 1 : 0;
    const int hp0 = tid - (hh0 ? HP : 0);
    const int hy0 = hp0 / HS, hx0 = hp0 - hy0 * HS;
    const int gy0 = y0 + hy0 - 3, gx0 = x0 + hx0 - 3;
    const bool ok0 = ((unsigned)gy0 < 64u) && ((unsigned)gx0 < 64u);

    const int hp1 = tid + 28;
    const int hy1 = hp1 / HS, hx1 = hp1 - hy1 * HS;
    const int gy1 = y0 + hy1 - 3, gx1 = x0 + hx1 - 3;
    const bool it1v = (tid < 2 * HP - 512);
    const bool ok1 = it1v && ((unsigned)gy1 < 64u) && ((unsigned)gx1 < 64u);

    float xr0[32], xr1[32];
    #pragma unroll
    for (int ci = 0; ci < 32; ++ci) { xr0[ci] = 0.f; xr1[ci] = 0.f; }
    if (ok0) {
        const float* xp = xg + gy0 * 64 + gx0;
        #pragma unroll
        for (int ci = 0; ci < 32; ++ci) xr0[ci] = xp[ci * 4096];
    }
    if (ok1) {
        const float* xp = xg + gy1 * 64 + gx1;
        #pragma unroll
        for (int ci = 0; ci < 32; ++ci) xr1[ci] = xp[ci * 4096];
    }

    // ---- stage all 3 weight matrices as f16 pairs + emb slice ----
    {
        const int cp  = tid & 15;
        const int cog = tid >> 4;
        const int hh  = cog >> 4;
        const int co  = cog & 15;
        const int di  = (hh * 16 + cp) * 16 + co;
        const float2* wk2 = (const float2*)(wk + g * 1024);
        const float2* wv2 = (const float2*)(wv + g * 1024);
        const float2* wq2 = (const float2*)(wq + g * 1024);
        float2 a = wk2[tid]; s_w[di]        = pkrtz(a.x, a.y);
        float2 v = wv2[tid]; s_w[512 + di]  = pkrtz(v.x, v.y);
        float2 q = wq2[tid]; s_w[1024 + di] = pkrtz(q.x, q.y);
    }
    if (tid < 224) {
        int c = tid / KK, t = tid - c * KK;
        s_emb[tid] = (g < 4) ? row_emb[(g * 32 + c) * KK + t]
                             : col_emb[((g - 4) * 32 + c) * KK + t];
    }
    __syncthreads();   // weights staged; x loads also drained (in regs)

    // ---- item0 projection: 32 accs via dot2, b128 weight-row broadcasts ----
    {
        h2 xv2[16];
        #pragma unroll
        for (int cp = 0; cp < 16; ++cp) xv2[cp] = pkrtz(xr0[2 * cp], xr0[2 * cp + 1]);
        float accK[16], accV[16];
        #pragma unroll
        for (int c = 0; c < 16; ++c) { accK[c] = 0.f; accV[c] = 0.f; }
        const h2* wkp = s_w + hh0 * 256;
        const h2* wvp = s_w + 512 + hh0 * 256;
        #pragma unroll
        for (int cp = 0; cp < 16; ++cp) {
            h2 xv = xv2[cp];
            const uint4* wkr = (const uint4*)(wkp + cp * 16);
            const uint4* wvr = (const uint4*)(wvp + cp * 16);
            uint4 kw[4] = { wkr[0], wkr[1], wkr[2], wkr[3] };
            uint4 vw[4] = { wvr[0], wvr[1], wvr[2], wvr[3] };
            const unsigned* kwu = (const unsigned*)kw;
            const unsigned* vwu = (const unsigned*)vw;
            #pragma unroll
            for (int co = 0; co < 16; ++co) {
                accK[co] = dot2u(kwu[co], xv, accK[co]);
                accV[co] = dot2u(vwu[co], xv, accV[co]);
            }
        }
        unsigned* dk = s_ku + hp0 * KDW + hh0 * 8;
        unsigned* dv = s_vu + hp0 * KDW + hh0 * 8;
        #pragma unroll
        for (int j = 0; j < 4; ++j) {
            U32H a0, a1, b0, b1;
            a0.h = pkrtz(accK[4 * j],     accK[4 * j + 1]);
            a1.h = pkrtz(accK[4 * j + 2], accK[4 * j + 3]);
            b0.h = pkrtz(accV[4 * j],     accV[4 * j + 1]);
            b1.h = pkrtz(accV[4 * j + 2], accV[4 * j + 3]);
            ((uint2*)dk)[j] = make_uint2(a0.u, a1.u);
            ((uint2*)dv)[j] = make_uint2(b0.u, b1.u);
        }
    }
    // ---- item1 projection (hh=1) ----
    if (it1v) {
        h2 xv2[16];
        #pragma unroll
        for (int cp = 0; cp < 16; ++cp) xv2[cp] = pkrtz(xr1[2 * cp], xr1[2 * cp + 1]);
        float accK[16], accV[16];
        #pragma unroll
        for (int c = 0; c < 16; ++c) { accK[c] = 0.f; accV[c] = 0.f; }
        const h2* wkp = s_w + 256;
        const h2* wvp = s_w + 512 + 256;
        #pragma unroll
        for (int cp = 0; cp < 16; ++cp) {
            h2 xv = xv2[cp];
            const uint4* wkr = (const uint4*)(wkp + cp * 16);
            const uint4* wvr = (const uint4*)(wvp + cp * 16);
            uint4 kw[4] = { wkr[0], wkr[1], wkr[2], wkr[3] };
            uint4 vw[4] = { wvr[0], wvr[1], wvr[2], wvr[3] };
            const unsigned* kwu = (const unsigned*)kw;
            const unsigned* vwu = (const unsigned*)vw;
            #pragma unroll
            for (int co = 0; co < 16; ++co) {
                accK[co] = dot2u(kwu[co], xv, accK[co]);
                accV[co] = dot2u(vwu[co], xv, accV[co]);
            }
        }
        unsigned* dk = s_ku + hp1 * KDW + 8;
        unsigned* dv = s_vu + hp1 * KDW + 8;
        #pragma unroll
        for (int j = 0; j < 4; ++j) {
            U32H a0, a1, b0, b1;
            a0.h = pkrtz(accK[4 * j],     accK[4 * j + 1]);
            a1.h = pkrtz(accK[4 * j + 2], accK[4 * j + 3]);
            b0.h = pkrtz(accV[4 * j],     accV[4 * j + 1]);
            b1.h = pkrtz(accV[4 * j + 2], accV[4 * j + 3]);
            ((uint2*)dk)[j] = make_uint2(a0.u, a1.u);
            ((uint2*)dv)[j] = make_uint2(b0.u, b1.u);
        }
    }

    // ---- q projection: thread (p, h) owns 16 q channels ----
    const int p  = tid >> 1;
    const int h  = tid & 1;
    const int tx = p & 15, ty = p >> 4;
    const int yy = y0 + ty, xx = x0 + tx;
    float accQ[16];
    #pragma unroll
    for (int c = 0; c < 16; ++c) accQ[c] = 0.f;
    {
        const float* xp = xg + yy * 64 + xx;
        h2 xv2[16];
        #pragma unroll
        for (int cp = 0; cp < 16; ++cp)
            xv2[cp] = pkrtz(xp[(2 * cp) * 4096], xp[(2 * cp + 1) * 4096]);
        const h2* wqp = s_w + 1024 + h * 256;
        #pragma unroll
        for (int cp = 0; cp < 16; ++cp) {
            h2 xv = xv2[cp];
            const uint4* wqr = (const uint4*)(wqp + cp * 16);
            uint4 qw[4] = { wqr[0], wqr[1], wqr[2], wqr[3] };
            const unsigned* qwu = (const unsigned*)qw;
            #pragma unroll
            for (int co = 0; co < 16; ++co)
                accQ[co] = dot2u(qwu[co], xv, accQ[co]);
        }
    }

    // ---- qe[7] = q . emb, pair-combined (both lanes end with the full value) ----
    float qe[KK];
    #pragma unroll
    for (int t = 0; t < KK; ++t) {
        float a = 0.f;
        #pragma unroll
        for (int c = 0; c < 16; ++c)
            a = fmaf(accQ[c], s_emb[(h * 16 + c) * KK + t], a);
        qe[t] = a;
    }
    #pragma unroll
    for (int t = 0; t < KK; ++t)
        qe[t] += __shfl_xor(qe[t], 1, 64);

    // ---- pack q to f16 pairs ----
    h2 q2[8];
    #pragma unroll
    for (int j = 0; j < 8; ++j) q2[j] = pkrtz(accQ[2 * j], accQ[2 * j + 1]);

    __syncthreads();   // s_ku / s_vu complete

    const int rowsel = (g < 4) ? 1 : 0;

    // ---- Phase A: all 49 logits (b64 K reads; independent, pipelined) ----
    float lg[K2];
    const unsigned* kb = s_ku + h * 8;
    #pragma unroll
    for (int ki = 0; ki < KK; ++ki) {
        #pragma unroll
        for (int kj = 0; kj < KK; ++kj) {
            const int hp = (ty + ki) * HS + tx + kj;
            const uint2* kp = (const uint2*)(kb + hp * KDW);
            uint2 w0 = kp[0], w1 = kp[1], w2 = kp[2], w3 = kp[3];
            float part = 0.f;
            part = dot2u(w0.x, q2[0], part);
            part = dot2u(w0.y, q2[1], part);
            part = dot2u(w1.x, q2[2], part);
            part = dot2u(w1.y, q2[3], part);
            part = dot2u(w2.x, q2[4], part);
            part = dot2u(w2.y, q2[5], part);
            part = dot2u(w3.x, q2[6], part);
            part = dot2u(w3.y, q2[7], part);
            lg[ki * KK + kj] = part + __shfl_xor(part, 1, 64)
                             + (rowsel ? qe[ki] : qe[kj]);
        }
    }

    // ---- Phase B: tree max, independent exps, tree sum ----
    float m0 = lg[0], m1 = lg[1], m2 = lg[2], m3 = lg[3];
    #pragma unroll
    for (int t = 4; t < 48; t += 4) {
        m0 = fmaxf(m0, lg[t]);
        m1 = fmaxf(m1, lg[t + 1]);
        m2 = fmaxf(m2, lg[t + 2]);
        m3 = fmaxf(m3, lg[t + 3]);
    }
    const float mx = fmaxf(fmaxf(m0, m1), fmaxf(m2, fmaxf(m3, lg[48])));

    float s0 = 0.f, s1 = 0.f, s2 = 0.f, s3 = 0.f;
    #pragma unroll
    for (int t = 0; t < K2; ++t) {
        float pe = __expf(lg[t] - mx);
        lg[t] = pe;
        if ((t & 3) == 0) s0 += pe;
        else if ((t & 3) == 1) s1 += pe;
        else if ((t & 3) == 2) s2 += pe;
        else s3 += pe;
    }
    const float s = (s0 + s1) + (s2 + s3);

    // ---- PV: b64 V reads, pure f16 fma accumulation ----
    __half2 o2[8];
    #pragma unroll
    for (int j = 0; j < 8; ++j) o2[j] = __float2half2_rn(0.f);

    const unsigned* vb = s_vu + h * 8;
    #pragma unroll
    for (int ki = 0; ki < KK; ++ki) {
        #pragma unroll
        for (int kj = 0; kj < KK; ++kj) {
            const int hp = (ty + ki) * HS + tx + kj;
            const uint2* vp = (const uint2*)(vb + hp * KDW);
            uint2 w0 = vp[0], w1 = vp[1], w2 = vp[2], w3 = vp[3];
            const __half2 pe2 = __float2half2_rn(lg[ki * KK + kj]);
            U32H c0, c1, c2, c3, c4, c5, c6, c7;
            c0.u = w0.x; c1.u = w0.y; c2.u = w1.x; c3.u = w1.y;
            c4.u = w2.x; c5.u = w2.y; c6.u = w3.x; c7.u = w3.y;
            o2[0] = __hfma2(c0.p, pe2, o2[0]);
            o2[1] = __hfma2(c1.p, pe2, o2[1]);
            o2[2] = __hfma2(c2.p, pe2, o2[2]);
            o2[3] = __hfma2(c3.p, pe2, o2[3]);
            o2[4] = __hfma2(c4.p, pe2, o2[4]);
            o2[5] = __hfma2(c5.p, pe2, o2[5]);
            o2[6] = __hfma2(c6.p, pe2, o2[6]);
            o2[7] = __hfma2(c7.p, pe2, o2[7]);
        }
    }

    // ---- write 16 channels ----
    const float inv = 1.0f / s;
    float* op = out + (size_t)(b * 256 + g * 32 + h * 16) * 4096 + yy * 64 + xx;
    #pragma unroll
    for (int j = 0; j < 8; ++j) {
        float2 f = __half22float2(o2[j]);
        op[(2 * j) * 4096]     = f.x * inv;
        op[(2 * j + 1) * 4096] = f.y * inv;
    }
}

extern "C" void kernel_launch(void* const* d_in, const int* in_sizes, int n_in,
                              void* d_out, int out_size, void* d_ws, size_t ws_size,
                              hipStream_t stream) {
    const float* x       = (const float*)d_in[0];
    const float* wq      = (const float*)d_in[1];
    const float* wk      = (const float*)d_in[2];
    const float* wv      = (const float*)d_in[3];
    const float* row_emb = (const float*)d_in[4];
    const float* col_emb = (const float*)d_in[5];
    float* out = (float*)d_out;

    dim3 grid(4, 4, 32);   // remapped inside kernel (XCD-bijective swizzle)
    dim3 block(512);
    sasa_fused_kernel<<<grid, block, 0, stream>>>(x, wq, wk, wv, row_emb, col_emb, out);
}

// Round 16
// 49.873 us; speedup vs baseline: 6.0141x; 1.0314x over previous
//
#include <hip/hip_runtime.h>
#include <hip/hip_bf16.h>
#include <hip/hip_fp16.h>

// SASA local self-attention, fused. Round 16: ILP/latency attack.
//  - amdgpu_waves_per_eu(4,4): occupancy is LDS-capped at 4 waves/EU anyway ->
//    let the allocator use up to 128 VGPRs (was 64, ILP-starved)
//  - pair-wise software pipeline in Phase A / PV (2 positions in flight)
//  - lane^1 exchange via DPP quad_perm (VALU) instead of ds_bpermute (LDS pipe)
// B=4, CIN=COUT=256, H=W=64, G=8, CG=32, K=7, PAD=3.
#define TS   16
#define HS   22
#define HP   484
#define KDW  18          // u32 stride per halo pixel (72B)
#define KK   7
#define K2   49

typedef _Float16 h2 __attribute__((ext_vector_type(2)));
union U32H { unsigned u; h2 h; __half2 p; };

__device__ __forceinline__ h2 pkrtz(float a, float b) {
    auto r = __builtin_amdgcn_cvt_pkrtz(a, b);     // __fp16 vec2 on this clang
    union { decltype(r) i; h2 o; } c; c.i = r;     // same bits, retype
    return c.o;
}
__device__ __forceinline__ float dot2(h2 a, h2 b, float c) {
#if __has_builtin(__builtin_amdgcn_fdot2)
    return __builtin_amdgcn_fdot2(a, b, c, false);
#else
    return fmaf((float)a.x, (float)b.x, fmaf((float)a.y, (float)b.y, c));
#endif
}
__device__ __forceinline__ float dot2u(unsigned wu, h2 b, float c) {
    U32H w; w.u = wu; return dot2(w.h, b, c);
}
// v = value from lane^1 (quad_perm[1,0,3,2], VALU pipe, no LDS)
__device__ __forceinline__ float pswap(float v) {
#if __has_builtin(__builtin_amdgcn_mov_dpp)
    int j = __builtin_amdgcn_mov_dpp(__float_as_int(v), 0xB1, 0xF, 0xF, true);
    return __int_as_float(j);
#else
    return __shfl_xor(v, 1, 64);
#endif
}

__global__ __attribute__((amdgpu_flat_work_group_size(512, 512), amdgpu_waves_per_eu(4, 4)))
void sasa_fused_kernel(const float* __restrict__ x,
                       const float* __restrict__ wq,
                       const float* __restrict__ wk,
                       const float* __restrict__ wv,
                       const float* __restrict__ row_emb,
                       const float* __restrict__ col_emb,
                       float* __restrict__ out)
{
    __shared__ h2       s_w[1536];         // [m(k,v,q)*2+hh][cp][co], 6 KB
    __shared__ float    s_emb[224];        // E[c][t], 0.9 KB
    __shared__ unsigned s_ku[HP * KDW];    // K halo, f16 pairs, 34.8 KB
    __shared__ unsigned s_vu[HP * KDW];    // V halo, f16 pairs, 34.8 KB

    const int tid = threadIdx.x;

    // ---- XCD-bijective swizzle: 16 spatial tiles of each (b,g) share an XCD ----
    const int lin  = blockIdx.x + (blockIdx.y << 2) + (blockIdx.z << 4); // [0,512)
    const int xcd  = lin & 7;
    const int slot = lin >> 3;
    const int zg   = xcd + ((slot >> 4) << 3);
    const int sp   = slot & 15;
    const int b    = zg >> 3;
    const int g    = zg & 7;
    const int y0   = (sp >> 2) * TS;
    const int x0   = (sp & 3) * TS;

    const float* xg = x + (size_t)(b * 256 + g * 32) * 4096;

    // ---- pre-issue projection x loads (both items) ----
    const int hh0 = (tid >= HP) ? 1 : 0;
    const int hp0 = tid - (hh0 ? HP : 0);
    const int hy0 = hp0 / HS, hx0 = hp0 - hy0 * HS;
    const int gy0 = y0 + hy0 - 3, gx0 = x0 + hx0 - 3;
    const bool ok0 = ((unsigned)gy0 < 64u) && ((unsigned)gx0 < 64u);

    const int hp1 = tid + 28;
    const int hy1 = hp1 / HS, hx1 = hp1 - hy1 * HS;
    const int gy1 = y0 + hy1 - 3, gx1 = x0 + hx1 - 3;
    const bool it1v = (tid < 2 * HP - 512);
    const bool ok1 = it1v && ((unsigned)gy1 < 64u) && ((unsigned)gx1 < 64u);

    float xr0[32], xr1[32];
    #pragma unroll
    for (int ci = 0; ci < 32; ++ci) { xr0[ci] = 0.f; xr1[ci] = 0.f; }
    if (ok0) {
        const float* xp = xg + gy0 * 64 + gx0;
        #pragma unroll
        for (int ci = 0; ci < 32; ++ci) xr0[ci] = xp[ci * 4096];
    }
    if (ok1) {
        const float* xp = xg + gy1 * 64 + gx1;
        #pragma unroll
        for (int ci = 0; ci < 32; ++ci) xr1[ci] = xp[ci * 4096];
    }

    // ---- stage all 3 weight matrices as f16 pairs + emb slice ----
    {
        const int cp  = tid & 15;
        const int cog = tid >> 4;
        const int hh  = cog >> 4;
        const int co  = cog & 15;
        const int di  = (hh * 16 + cp) * 16 + co;
        const float2* wk2 = (const float2*)(wk + g * 1024);
        const float2* wv2 = (const float2*)(wv + g * 1024);
        const float2* wq2 = (const float2*)(wq + g * 1024);
        float2 a = wk2[tid]; s_w[di]        = pkrtz(a.x, a.y);
        float2 v = wv2[tid]; s_w[512 + di]  = pkrtz(v.x, v.y);
        float2 q = wq2[tid]; s_w[1024 + di] = pkrtz(q.x, q.y);
    }
    if (tid < 224) {
        int c = tid / KK, t = tid - c * KK;
        s_emb[tid] = (g < 4) ? row_emb[(g * 32 + c) * KK + t]
                             : col_emb[((g - 4) * 32 + c) * KK + t];
    }
    __syncthreads();

    // ---- item0 projection ----
    {
        h2 xv2[16];
        #pragma unroll
        for (int cp = 0; cp < 16; ++cp) xv2[cp] = pkrtz(xr0[2 * cp], xr0[2 * cp + 1]);
        float accK[16], accV[16];
        #pragma unroll
        for (int c = 0; c < 16; ++c) { accK[c] = 0.f; accV[c] = 0.f; }
        const h2* wkp = s_w + hh0 * 256;
        const h2* wvp = s_w + 512 + hh0 * 256;
        #pragma unroll
        for (int cp = 0; cp < 16; ++cp) {
            h2 xv = xv2[cp];
            const uint4* wkr = (const uint4*)(wkp + cp * 16);
            const uint4* wvr = (const uint4*)(wvp + cp * 16);
            uint4 kw[4] = { wkr[0], wkr[1], wkr[2], wkr[3] };
            uint4 vw[4] = { wvr[0], wvr[1], wvr[2], wvr[3] };
            const unsigned* kwu = (const unsigned*)kw;
            const unsigned* vwu = (const unsigned*)vw;
            #pragma unroll
            for (int co = 0; co < 16; ++co) {
                accK[co] = dot2u(kwu[co], xv, accK[co]);
                accV[co] = dot2u(vwu[co], xv, accV[co]);
            }
        }
        unsigned* dk = s_ku + hp0 * KDW + hh0 * 8;
        unsigned* dv = s_vu + hp0 * KDW + hh0 * 8;
        #pragma unroll
        for (int j = 0; j < 4; ++j) {
            U32H a0, a1, b0, b1;
            a0.h = pkrtz(accK[4 * j],     accK[4 * j + 1]);
            a1.h = pkrtz(accK[4 * j + 2], accK[4 * j + 3]);
            b0.h = pkrtz(accV[4 * j],     accV[4 * j + 1]);
            b1.h = pkrtz(accV[4 * j + 2], accV[4 * j + 3]);
            ((uint2*)dk)[j] = make_uint2(a0.u, a1.u);
            ((uint2*)dv)[j] = make_uint2(b0.u, b1.u);
        }
    }
    // ---- item1 projection (hh=1) ----
    if (it1v) {
        h2 xv2[16];
        #pragma unroll
        for (int cp = 0; cp < 16; ++cp) xv2[cp] = pkrtz(xr1[2 * cp], xr1[2 * cp + 1]);
        float accK[16], accV[16];
        #pragma unroll
        for (int c = 0; c < 16; ++c) { accK[c] = 0.f; accV[c] = 0.f; }
        const h2* wkp = s_w + 256;
        const h2* wvp = s_w + 512 + 256;
        #pragma unroll
        for (int cp = 0; cp < 16; ++cp) {
            h2 xv = xv2[cp];
            const uint4* wkr = (const uint4*)(wkp + cp * 16);
            const uint4* wvr = (const uint4*)(wvp + cp * 16);
            uint4 kw[4] = { wkr[0], wkr[1], wkr[2], wkr[3] };
            uint4 vw[4] = { wvr[0], wvr[1], wvr[2], wvr[3] };
            const unsigned* kwu = (const unsigned*)kw;
            const unsigned* vwu = (const unsigned*)vw;
            #pragma unroll
            for (int co = 0; co < 16; ++co) {
                accK[co] = dot2u(kwu[co], xv, accK[co]);
                accV[co] = dot2u(vwu[co], xv, accV[co]);
            }
        }
        unsigned* dk = s_ku + hp1 * KDW + 8;
        unsigned* dv = s_vu + hp1 * KDW + 8;
        #pragma unroll
        for (int j = 0; j < 4; ++j) {
            U32H a0, a1, b0, b1;
            a0.h = pkrtz(accK[4 * j],     accK[4 * j + 1]);
            a1.h = pkrtz(accK[4 * j + 2], accK[4 * j + 3]);
            b0.h = pkrtz(accV[4 * j],     accV[4 * j + 1]);
            b1.h = pkrtz(accV[4 * j + 2], accV[4 * j + 3]);
            ((uint2*)dk)[j] = make_uint2(a0.u, a1.u);
            ((uint2*)dv)[j] = make_uint2(b0.u, b1.u);
        }
    }

    // ---- q projection: thread (p, h) owns 16 q channels ----
    const int p  = tid >> 1;
    const int h  = tid & 1;
    const int tx = p & 15, ty = p >> 4;
    const int yy = y0 + ty, xx = x0 + tx;
    float accQ[16];
    #pragma unroll
    for (int c = 0; c < 16; ++c) accQ[c] = 0.f;
    {
        const float* xp = xg + yy * 64 + xx;
        h2 xv2[16];
        #pragma unroll
        for (int cp = 0; cp < 16; ++cp)
            xv2[cp] = pkrtz(xp[(2 * cp) * 4096], xp[(2 * cp + 1) * 4096]);
        const h2* wqp = s_w + 1024 + h * 256;
        #pragma unroll
        for (int cp = 0; cp < 16; ++cp) {
            h2 xv = xv2[cp];
            const uint4* wqr = (const uint4*)(wqp + cp * 16);
            uint4 qw[4] = { wqr[0], wqr[1], wqr[2], wqr[3] };
            const unsigned* qwu = (const unsigned*)qw;
            #pragma unroll
            for (int co = 0; co < 16; ++co)
                accQ[co] = dot2u(qwu[co], xv, accQ[co]);
        }
    }

    // ---- qe[7] = q . emb, pair-combined via DPP ----
    float qe[KK];
    #pragma unroll
    for (int t = 0; t < KK; ++t) {
        float a = 0.f;
        #pragma unroll
        for (int c = 0; c < 16; ++c)
            a = fmaf(accQ[c], s_emb[(h * 16 + c) * KK + t], a);
        qe[t] = a + 0.f;
    }
    #pragma unroll
    for (int t = 0; t < KK; ++t)
        qe[t] += pswap(qe[t]);

    // ---- pack q to f16 pairs ----
    h2 q2[8];
    #pragma unroll
    for (int j = 0; j < 8; ++j) q2[j] = pkrtz(accQ[2 * j], accQ[2 * j + 1]);

    __syncthreads();   // s_ku / s_vu complete

    const int rowsel = (g < 4) ? 1 : 0;

    // ---- Phase A: 49 logits, 2 positions in flight, DPP pair-combine ----
    float lg[K2];
    const unsigned* kb = s_ku + h * 8;
    #pragma unroll
    for (int tp = 0; tp < 24; ++tp) {
        const int t0 = 2 * tp, t1 = t0 + 1;
        const int ki0 = t0 / KK, kj0 = t0 - ki0 * KK;
        const int ki1 = t1 / KK, kj1 = t1 - ki1 * KK;
        const uint2* kp0 = (const uint2*)(kb + ((ty + ki0) * HS + tx + kj0) * KDW);
        const uint2* kp1 = (const uint2*)(kb + ((ty + ki1) * HS + tx + kj1) * KDW);
        uint2 a0 = kp0[0], a1 = kp0[1], a2 = kp0[2], a3 = kp0[3];
        uint2 b0 = kp1[0], b1 = kp1[1], b2 = kp1[2], b3 = kp1[3];
        float p0 = 0.f, p1 = 0.f;
        p0 = dot2u(a0.x, q2[0], p0);  p1 = dot2u(b0.x, q2[0], p1);
        p0 = dot2u(a0.y, q2[1], p0);  p1 = dot2u(b0.y, q2[1], p1);
        p0 = dot2u(a1.x, q2[2], p0);  p1 = dot2u(b1.x, q2[2], p1);
        p0 = dot2u(a1.y, q2[3], p0);  p1 = dot2u(b1.y, q2[3], p1);
        p0 = dot2u(a2.x, q2[4], p0);  p1 = dot2u(b2.x, q2[4], p1);
        p0 = dot2u(a2.y, q2[5], p0);  p1 = dot2u(b2.y, q2[5], p1);
        p0 = dot2u(a3.x, q2[6], p0);  p1 = dot2u(b3.x, q2[6], p1);
        p0 = dot2u(a3.y, q2[7], p0);  p1 = dot2u(b3.y, q2[7], p1);
        lg[t0] = p0 + pswap(p0) + (rowsel ? qe[ki0] : qe[kj0]);
        lg[t1] = p1 + pswap(p1) + (rowsel ? qe[ki1] : qe[kj1]);
    }
    {   // t = 48 (ki=6, kj=6)
        const uint2* kp = (const uint2*)(kb + ((ty + 6) * HS + tx + 6) * KDW);
        uint2 a0 = kp[0], a1 = kp[1], a2 = kp[2], a3 = kp[3];
        float p0 = 0.f;
        p0 = dot2u(a0.x, q2[0], p0); p0 = dot2u(a0.y, q2[1], p0);
        p0 = dot2u(a1.x, q2[2], p0); p0 = dot2u(a1.y, q2[3], p0);
        p0 = dot2u(a2.x, q2[4], p0); p0 = dot2u(a2.y, q2[5], p0);
        p0 = dot2u(a3.x, q2[6], p0); p0 = dot2u(a3.y, q2[7], p0);
        lg[48] = p0 + pswap(p0) + qe[6];
    }

    // ---- Phase B: tree max, independent exps, tree sum ----
    float m0 = lg[0], m1 = lg[1], m2 = lg[2], m3 = lg[3];
    #pragma unroll
    for (int t = 4; t < 48; t += 4) {
        m0 = fmaxf(m0, lg[t]);
        m1 = fmaxf(m1, lg[t + 1]);
        m2 = fmaxf(m2, lg[t + 2]);
        m3 = fmaxf(m3, lg[t + 3]);
    }
    const float mx = fmaxf(fmaxf(m0, m1), fmaxf(m2, fmaxf(m3, lg[48])));

    float s0 = 0.f, s1 = 0.f, s2 = 0.f, s3 = 0.f;
    #pragma unroll
    for (int t = 0; t < K2; ++t) {
        float pe = __expf(lg[t] - mx);
        lg[t] = pe;
        if ((t & 3) == 0) s0 += pe;
        else if ((t & 3) == 1) s1 += pe;
        else if ((t & 3) == 2) s2 += pe;
        else s3 += pe;
    }
    const float s = (s0 + s1) + (s2 + s3);

    // ---- PV: 2 positions in flight, pure f16 fma accumulation ----
    __half2 o2[8];
    #pragma unroll
    for (int j = 0; j < 8; ++j) o2[j] = __float2half2_rn(0.f);

    const unsigned* vb = s_vu + h * 8;
    #pragma unroll
    for (int tp = 0; tp < 24; ++tp) {
        const int t0 = 2 * tp, t1 = t0 + 1;
        const int ki0 = t0 / KK, kj0 = t0 - ki0 * KK;
        const int ki1 = t1 / KK, kj1 = t1 - ki1 * KK;
        const uint2* vp0 = (const uint2*)(vb + ((ty + ki0) * HS + tx + kj0) * KDW);
        const uint2* vp1 = (const uint2*)(vb + ((ty + ki1) * HS + tx + kj1) * KDW);
        uint2 a0 = vp0[0], a1 = vp0[1], a2 = vp0[2], a3 = vp0[3];
        uint2 b0 = vp1[0], b1 = vp1[1], b2 = vp1[2], b3 = vp1[3];
        const __half2 pe0 = __float2half2_rn(lg[t0]);
        const __half2 pe1 = __float2half2_rn(lg[t1]);
        U32H c0, c1, c2, c3, c4, c5, c6, c7;
        c0.u = a0.x; c1.u = a0.y; c2.u = a1.x; c3.u = a1.y;
        c4.u = a2.x; c5.u = a2.y; c6.u = a3.x; c7.u = a3.y;
        o2[0] = __hfma2(c0.p, pe0, o2[0]);
        o2[1] = __hfma2(c1.p, pe0, o2[1]);
        o2[2] = __hfma2(c2.p, pe0, o2[2]);
        o2[3] = __hfma2(c3.p, pe0, o2[3]);
        o2[4] = __hfma2(c4.p, pe0, o2[4]);
        o2[5] = __hfma2(c5.p, pe0, o2[5]);
        o2[6] = __hfma2(c6.p, pe0, o2[6]);
        o2[7] = __hfma2(c7.p, pe0, o2[7]);
        c0.u = b0.x; c1.u = b0.y; c2.u = b1.x; c3.u = b1.y;
        c4.u = b2.x; c5.u = b2.y; c6.u = b3.x; c7.u = b3.y;
        o2[0] = __hfma2(c0.p, pe1, o2[0]);
        o2[1] = __hfma2(c1.p, pe1, o2[1]);
        o2[2] = __hfma2(c2.p, pe1, o2[2]);
        o2[3] = __hfma2(c3.p, pe1, o2[3]);
        o2[4] = __hfma2(c4.p, pe1, o2[4]);
        o2[5] = __hfma2(c5.p, pe1, o2[5]);
        o2[6] = __hfma2(c6.p, pe1, o2[6]);
        o2[7] = __hfma2(c7.p, pe1, o2[7]);
    }
    {   // t = 48
        const uint2* vp = (const uint2*)(vb + ((ty + 6) * HS + tx + 6) * KDW);
        uint2 a0 = vp[0], a1 = vp[1], a2 = vp[2], a3 = vp[3];
        const __half2 pe0 = __float2half2_rn(lg[48]);
        U32H c0, c1, c2, c3, c4, c5, c6, c7;
        c0.u = a0.x; c1.u = a0.y; c2.u = a1.x; c3.u = a1.y;
        c4.u = a2.x; c5.u = a2.y; c6.u = a3.x; c7.u = a3.y;
        o2[0] = __hfma2(c0.p, pe0, o2[0]);
        o2[1] = __hfma2(c1.p, pe0, o2[1]);
        o2[2] = __hfma2(c2.p, pe0, o2[2]);
        o2[3] = __hfma2(c3.p, pe0, o2[3]);
        o2[4] = __hfma2(c4.p, pe0, o2[4]);
        o2[5] = __hfma2(c5.p, pe0, o2[5]);
        o2[6] = __hfma2(c6.p, pe0, o2[6]);
        o2[7] = __hfma2(c7.p, pe0, o2[7]);
    }

    // ---- write 16 channels ----
    const float inv = 1.0f / s;
    float* op = out + (size_t)(b * 256 + g * 32 + h * 16) * 4096 + yy * 64 + xx;
    #pragma unroll
    for (int j = 0; j < 8; ++j) {
        float2 f = __half22float2(o2[j]);
        op[(2 * j) * 4096]     = f.x * inv;
        op[(2 * j + 1) * 4096] = f.y * inv;
    }
}

extern "C" void kernel_launch(void* const* d_in, const int* in_sizes, int n_in,
                              void* d_out, int out_size, void* d_ws, size_t ws_size,
                              hipStream_t stream) {
    const float* x       = (const float*)d_in[0];
    const float* wq      = (const float*)d_in[1];
    const float* wk      = (const float*)d_in[2];
    const float* wv      = (const float*)d_in[3];
    const float* row_emb = (const float*)d_in[4];
    const float* col_emb = (const float*)d_in[5];
    float* out = (float*)d_out;

    dim3 grid(4, 4, 32);   // remapped inside kernel (XCD-bijective swizzle)
    dim3 block(512);
    sasa_fused_kernel<<<grid, block, 0, stream>>>(x, wq, wk, wv, row_emb, col_emb, out);
}